// Round 3
// baseline (193.246 us; speedup 1.0000x reference)
//
#include <hip/hip_runtime.h>

typedef unsigned short u16;
typedef __attribute__((ext_vector_type(8))) short short8;
typedef __attribute__((ext_vector_type(4))) short short4v;
typedef __attribute__((ext_vector_type(4))) float f32x4;
typedef __attribute__((ext_vector_type(4))) float float4v;
typedef __attribute__((ext_vector_type(4))) unsigned short u16x4;

#define AS1 __attribute__((address_space(1)))
#define AS3 __attribute__((address_space(3)))

// B=2, T=2048, C=1024, H=16, HD=64
#define Tn 2048
#define Cn 1024
#define Hn 16
#define HDn 64

struct FalseT { static constexpr bool value = false; };
struct TrueT  { static constexpr bool value = true;  };

static __device__ __forceinline__ u16 f2bf(float f) {
    unsigned int u = __float_as_uint(f);
    u += 0x7FFFu + ((u >> 16) & 1u);   // round-to-nearest-even
    return (u16)(u >> 16);
}

static __device__ __forceinline__ void ldlds16(const void* g, void* l) {
    __builtin_amdgcn_global_load_lds((const AS1 unsigned int*)g,
                                     (AS3 unsigned int*)l, 16, 0, 0);
}

// ---------------- fused prep: x->bf16 | Wqkv^T->bf16 | Wo^T->bf16 ----------------
__global__ void prep(const float* __restrict__ x, u16* __restrict__ xb,
                     const float* __restrict__ Wqkv, u16* __restrict__ wqkvt,
                     const float* __restrict__ Wo, u16* __restrict__ wot) {
    __shared__ float t[64][65];
    const int bx = blockIdx.x, tid = threadIdx.x;
    if (bx < 4096) {
        int i = bx * 256 + tid;
        float4v v = ((const float4v*)x)[i];
        u16x4 o;
        o.x = f2bf(v.x); o.y = f2bf(v.y); o.z = f2bf(v.z); o.w = f2bf(v.w);
        ((u16x4*)xb)[i] = o;
        return;
    }
    const float* in; u16* out; int R, Cc, r0, c0;
    if (bx < 4864) {
        int idx = bx - 4096;
        in = Wqkv; out = wqkvt; R = 1024; Cc = 3072;
        c0 = (idx % 48) * 64; r0 = (idx / 48) * 64;
    } else {
        int idx = bx - 4864;
        in = Wo; out = wot; R = 1024; Cc = 1024;
        c0 = (idx & 15) * 64; r0 = (idx >> 4) * 64;
    }
    int tx = tid & 63, ty = tid >> 6;
#pragma unroll
    for (int i = 0; i < 64; i += 4)
        t[ty + i][tx] = in[(long)(r0 + ty + i) * Cc + c0 + tx];
    __syncthreads();
#pragma unroll
    for (int i = 0; i < 64; i += 4)
        out[(long)(c0 + ty + i) * R + r0 + tx] = f2bf(t[tx][ty + i]);
}

// ---------------- V transpose from combined qkv: -> vtb[bh][64][T] (bf16) ----------------
__global__ void transpose_v(const u16* __restrict__ qkv, u16* __restrict__ out) {
    __shared__ u16 t[64][65];
    int bh = blockIdx.y;
    int b = bh >> 4, h = bh & 15;
    int t0 = blockIdx.x * 64;
    const u16* inp = qkv + ((long)b * Tn + t0) * 3072 + 2048 + h * 64;
    u16* outp = out + (long)bh * Tn * HDn;
    int tx = threadIdx.x & 63, ty = threadIdx.x >> 6;
#pragma unroll
    for (int i = 0; i < 64; i += 4)
        t[ty + i][tx] = inp[(long)(ty + i) * 3072 + tx];
    __syncthreads();
#pragma unroll
    for (int i = 0; i < 64; i += 4)
        outp[(long)(ty + i) * Tn + t0 + tx] = t[tx][ty + i];
}

// ---------------- m97-style GEMM: C[M][N] = A[M][K] * Bt[N][K]^T + bias ----------------
// MODE 0: coalesced bf16 out[M][N], with softmax scale folded into Q columns (n<1024).
// MODE 1: fp32 out[M][N].
template <int MODE>
__global__ __launch_bounds__(256, 3)
void gemm_bt(const u16* __restrict__ A, const u16* __restrict__ Bt,
             const float* __restrict__ bias,
             u16* __restrict__ o16, float* __restrict__ f_out,
             int M, int N, int K) {
    __shared__ __attribute__((aligned(16))) u16 As[128 * 32];
    __shared__ __attribute__((aligned(16))) u16 Bs[128 * 32];
    const int tid = threadIdx.x;
    const int l = tid & 63;
    const int w = tid >> 6;
    const int wm = (w >> 1) * 64, wn = (w & 1) * 64;
    const long m0 = (long)blockIdx.x * 128, n0 = (long)blockIdx.y * 128;
    const int lm = l & 15, g = l >> 4;

    const int sr = tid >> 2;
    const int sc = (tid & 3) ^ ((tid >> 3) & 3);
    const u16* Ag = A + (m0 + sr) * K + sc * 8;
    const u16* Bg = Bt + (n0 + sr) * K + sc * 8;
    u16* Asl = As + tid * 8;
    u16* Bsl = Bs + tid * 8;

    const int x0 = (lm >> 1) & 3;

    f32x4 acc[4][4] = {};

    for (int k0 = 0; k0 < K; k0 += 32) {
        __syncthreads();
        ldlds16(Ag + k0, Asl);
        ldlds16(Ag + (long)64 * K + k0, Asl + 2048);
        ldlds16(Bg + k0, Bsl);
        ldlds16(Bg + (long)64 * K + k0, Bsl + 2048);
        __syncthreads();
        short8 af[4], bf[4];
#pragma unroll
        for (int mt = 0; mt < 4; ++mt)
            af[mt] = *(const short8*)(As + (wm + mt * 16 + lm) * 32 + ((g ^ x0) * 8));
#pragma unroll
        for (int nt = 0; nt < 4; ++nt)
            bf[nt] = *(const short8*)(Bs + (wn + nt * 16 + lm) * 32 + ((g ^ x0) * 8));
#pragma unroll
        for (int mt = 0; mt < 4; ++mt)
#pragma unroll
            for (int nt = 0; nt < 4; ++nt)
                acc[mt][nt] = __builtin_amdgcn_mfma_f32_16x16x32_bf16(
                    af[mt], bf[nt], acc[mt][nt], 0, 0, 0);
    }

    const int r0 = (l >> 4) * 4;
#pragma unroll
    for (int mt = 0; mt < 4; ++mt) {
#pragma unroll
        for (int nt = 0; nt < 4; ++nt) {
            long n = n0 + wn + nt * 16 + lm;
            float bv = bias[n];
            // fold softmax scale (0.125*log2e) into Q columns at MODE 0
            float scq = (MODE == 0 && n < 1024) ? 0.18033688f : 1.0f;
#pragma unroll
            for (int r = 0; r < 4; ++r) {
                long m = m0 + wm + mt * 16 + r0 + r;
                float v = (acc[mt][nt][r] + bv) * scq;
                if (MODE == 0) o16[m * N + n] = f2bf(v);
                else           f_out[m * N + n] = v;
            }
        }
    }
}

// ---------------- flash attention: S^T formulation, zero P round-trip ----------------
// 512 threads = 8 waves: 2-way q-split (mh: 32 rows, mt=2 tiles) x 4-way s-split
// (sh: 32 cols, nt=2 tiles). K-frags reused across mt, V-frags reused across mt ->
// LDS read traffic halved vs 4mh x 2sh. MFMA/exp2 counts identical.
// __launch_bounds__(512, 2): 128-VGPR cap. (512,4) capped at 64 VGPR -> the R2
// variant spilled ~27MB/dispatch to scratch (WRITE_SIZE 8->35MB). LDS already
// limits to 2 blocks/CU, so (512,2) costs no occupancy.
// Q pre-scaled by 0.125*log2e in gemm_bt<0> so softmax inner loop is bare exp2.
// Epilogue: 4-way cross-sh reduce via 3 padded [64][68] f32 LDS buffers (52 KB).
// LDS 64 KB: Ks[2] 128x64 @0/8192, Vs[2] 64x128 @16384/24576 (u16 idx).
__global__ __launch_bounds__(512, 2)
void attn(const u16* __restrict__ qkv, const u16* __restrict__ Vt,
          u16* __restrict__ Y) {
    __shared__ __attribute__((aligned(16))) u16 S_lds[32768];

    const int bh = blockIdx.y;
    const int px = blockIdx.x;             // 0..15
    const int tid = threadIdx.x, l = tid & 63, w = tid >> 6;   // w 0..7
    const int mh = w >> 2, sh = w & 3;     // 2 q-halves x 4 s-quarters
    const int lm = l & 15, g = l >> 4;
    const int lm7 = lm & 7;
    const int mh32 = mh * 32, sh32 = sh * 32, g4 = g * 4;
    const int b = bh >> 4, h = bh & 15;

    const u16* Kp = qkv + (long)b * Tn * 3072 + 1024 + h * 64;
    const u16* Vp = Vt + (long)bh * HDn * Tn;

    // 512-thread staging: K 64 rows/round (2 rounds), V 32 rows/round (2 rounds)
    const int soffK = (tid >> 3) * 3072 + (((tid & 7) ^ ((tid >> 3) & 7)) * 8);
    const int soffV = (tid >> 4) * Tn + (((tid & 15) ^ ((tid >> 4) & 15)) * 8);

    auto prefetch = [&](int i, int buf) {
        u16* Kn = S_lds + buf * 8192;
        u16* Vn = S_lds + 16384 + buf * 8192;
        const u16* Kt = Kp + (long)i * 128 * 3072;
        const u16* Vg = Vp + i * 128;
#pragma unroll
        for (int j = 0; j < 2; ++j) {
            ldlds16(Kt + j * (64 * 3072) + soffK, Kn + j * 4096 + tid * 8);
            ldlds16(Vg + j * (32 * Tn) + soffV, Vn + j * 4096 + tid * 8);
        }
    };

    for (int job = 0; job < 2; ++job) {
        const int qt = job ? px : 31 - px;
        const u16* Qp = qkv + ((long)b * Tn + qt * 64) * 3072 + h * 64;

        // Q fragments (B-operand of S^T mfma): Q[q=mh32+mt*16+lm][d=hh*32+g*8+j]
        short8 qa[2][2];
#pragma unroll
        for (int mt = 0; mt < 2; ++mt)
#pragma unroll
            for (int hh = 0; hh < 2; ++hh)
                qa[mt][hh] = *(const short8*)(Qp + (mh32 + mt * 16 + lm) * 3072 +
                                              hh * 32 + g * 8);

        f32x4 o_acc[2][4] = {};       // O^T[d=dt*16+g4+r][q=mh32+mt*16+lm]
        float lsum[2] = {0.f, 0.f};
        const int qrow0 = qt * 64 + mh32 + lm;

        prefetch(0, 0);
        __syncthreads();

        auto body = [&](int buf, int sbase, auto diag_c) {
            constexpr bool DIAG = decltype(diag_c)::value;
            const u16* Kc = S_lds + buf * 8192;
            const u16* Vc = S_lds + 16384 + buf * 8192;
            // S^T = K * Q^T : 2 q-tiles x 2 s-tiles, k=64; K-frag shared across mt
            f32x4 st[2][2];
#pragma unroll
            for (int mt = 0; mt < 2; ++mt)
#pragma unroll
                for (int nt = 0; nt < 2; ++nt)
                    st[mt][nt] = (f32x4){0.f, 0.f, 0.f, 0.f};
#pragma unroll
            for (int nt = 0; nt < 2; ++nt)
#pragma unroll
                for (int hh = 0; hh < 2; ++hh) {
                    short8 kf = *(const short8*)(Kc + (sh32 + nt * 16 + lm) * 64 +
                                                 (((hh * 4 + g) ^ lm7) * 8));
                    st[0][nt] = __builtin_amdgcn_mfma_f32_16x16x32_bf16(kf, qa[0][hh], st[0][nt], 0, 0, 0);
                    st[1][nt] = __builtin_amdgcn_mfma_f32_16x16x32_bf16(kf, qa[1][hh], st[1][nt], 0, 0, 0);
                }
            // exp2 + mask + pack to bf16 B-fragments (P^T stays in registers)
            short4v pb[2][2];
#pragma unroll
            for (int mt = 0; mt < 2; ++mt) {
                const int qrow = qrow0 + mt * 16;
#pragma unroll
                for (int nt = 0; nt < 2; ++nt) {
                    const int scolb = sbase + sh32 + nt * 16 + g4;
#pragma unroll
                    for (int r = 0; r < 4; ++r) {
                        float xx = st[mt][nt][r];
                        if (DIAG && scolb + r > qrow) xx = -1e30f;
                        float p = exp2f(xx);
                        lsum[mt] += p;
                        pb[mt][nt][r] = (short)(__float_as_uint(p) >> 16);
                    }
                }
            }
            // O^T += V^T * P^T : V-frag shared across mt
#pragma unroll
            for (int nt = 0; nt < 2; ++nt) {
                const int vcol = (((sh * 4 + nt * 2 + (g >> 1)) ^ lm) * 8) + (g & 1) * 4;
#pragma unroll
                for (int dt = 0; dt < 4; ++dt) {
                    short4v vf = *(const short4v*)(Vc + (dt * 16 + lm) * 128 + vcol);
                    o_acc[0][dt] = __builtin_amdgcn_mfma_f32_16x16x16bf16_1k(vf, pb[0][nt], o_acc[0][dt], 0, 0, 0);
                    o_acc[1][dt] = __builtin_amdgcn_mfma_f32_16x16x16bf16_1k(vf, pb[1][nt], o_acc[1][dt], 0, 0, 0);
                }
            }
        };

        const int n = (qt >> 1) + 1;     // 128-col iterations; last is DIAG
        if (n == 1) {
            body(0, 0, TrueT{});
        } else {
            int i = 0;
            for (; i + 2 <= n - 1; i += 2) {
                prefetch(i + 1, 1); body(0, i * 128, FalseT{}); __syncthreads();
                prefetch(i + 2, 0); body(1, (i + 1) * 128, FalseT{}); __syncthreads();
            }
            if (i == n - 2) {
                prefetch(n - 1, 1); body(0, i * 128, FalseT{}); __syncthreads();
                body(1, (n - 1) * 128, TrueT{});
            } else {  // i == n-1
                body(0, i * 128, TrueT{});
            }
        }

        // rowsum: sum across the 4 quads holding the same q=lm
#pragma unroll
        for (int mt = 0; mt < 2; ++mt) {
            lsum[mt] += __shfl_xor(lsum[mt], 16, 64);
            lsum[mt] += __shfl_xor(lsum[mt], 32, 64);
        }

        // ---- epilogue: 4-way cross-sh reduce + transpose via padded f32 LDS ----
        // B0/B1/B2 : [64][68] f32 at f32-offsets 0/4352/8704; redl3: 192 f32 @13056
        __syncthreads();
        float* Bf0  = (float*)S_lds;
        float* redl = Bf0 + 13056;

        if (sh != 0) {
            float* Bf = Bf0 + (sh - 1) * 4352;
#pragma unroll
            for (int mt = 0; mt < 2; ++mt) {
                const int q = mh32 + mt * 16 + lm;
#pragma unroll
                for (int dt = 0; dt < 4; ++dt)
                    *(f32x4*)(Bf + q * 68 + dt * 16 + g4) = o_acc[mt][dt];
                if (g == 0) redl[(sh - 1) * 64 + q] = lsum[mt];
            }
        }
        __syncthreads();
        if (sh == 0) {
#pragma unroll
            for (int mt = 0; mt < 2; ++mt) {
                const int q = mh32 + mt * 16 + lm;
                float inv = 1.0f / (lsum[mt] + redl[q] + redl[64 + q] + redl[128 + q]);
#pragma unroll
                for (int dt = 0; dt < 4; ++dt) {
                    f32x4 t = *(const f32x4*)(Bf0 + q * 68 + dt * 16 + g4);
                    t += *(const f32x4*)(Bf0 + 4352 + q * 68 + dt * 16 + g4);
                    t += *(const f32x4*)(Bf0 + 8704 + q * 68 + dt * 16 + g4);
                    t += o_acc[mt][dt];
                    t *= inv;
                    *(f32x4*)(Bf0 + q * 68 + dt * 16 + g4) = t;
                }
            }
        }
        __syncthreads();
        {   // coalesced store: 8 threads per q-row, 8 bf16 each
            const int q = tid >> 3, dseg = (tid & 7) * 8;
            long base = ((long)b * Tn + qt * 64 + q) * Cn + h * HDn + dseg;
            u16 tmp[8];
#pragma unroll
            for (int j = 0; j < 8; ++j)
                tmp[j] = f2bf(Bf0[q * 68 + dseg + j]);
            *(short8*)(Y + base) = *(const short8*)tmp;
        }
        __syncthreads();   // LDS reads done before next job restages
    }
}

extern "C" void kernel_launch(void* const* d_in, const int* in_sizes, int n_in,
                              void* d_out, int out_size, void* d_ws, size_t ws_size,
                              hipStream_t stream) {
    const float* x    = (const float*)d_in[0];
    const float* Wqkv = (const float*)d_in[1];
    const float* bqkv = (const float*)d_in[2];
    const float* Wo   = (const float*)d_in[3];
    const float* bo   = (const float*)d_in[4];
    float* out = (float*)d_out;

    u16* xb    = (u16*)d_ws;          // 4M u16 : x bf16
    u16* wqkvt = xb + 4194304;        // 3M : Wqkv^T
    u16* wot   = wqkvt + 3145728;     // 1M : Wo^T
    u16* qkvb  = wot + 1048576;       // 12M : qkv [b,t,3C] bf16 (Q pre-scaled)
    u16* vtb   = qkvb + 12582912;     // 4M : V^T [b,h,d,t]
    u16* yb    = vtb + 4194304;       // 4M : attn out [b,t,c]

    prep<<<5120, 256, 0, stream>>>(x, xb, Wqkv, wqkvt, Wo, wot);
    gemm_bt<0><<<dim3(32, 24), 256, 0, stream>>>(xb, wqkvt, bqkv, qkvb, nullptr,
                                                 4096, 3072, 1024);
    transpose_v<<<dim3(32, 32), 256, 0, stream>>>(qkvb, vtb);
    attn<<<dim3(16, 32), 512, 0, stream>>>(qkvb, vtb, yb);
    gemm_bt<1><<<dim3(32, 8), 256, 0, stream>>>(yb, wot, bo, nullptr, out,
                                                4096, 1024, 1024);
}

// Round 4
// 176.485 us; speedup vs baseline: 1.0950x; 1.0950x over previous
//
#include <hip/hip_runtime.h>

typedef unsigned short u16;
typedef __attribute__((ext_vector_type(8))) short short8;
typedef __attribute__((ext_vector_type(4))) short short4v;
typedef __attribute__((ext_vector_type(4))) float f32x4;
typedef __attribute__((ext_vector_type(4))) float float4v;
typedef __attribute__((ext_vector_type(4))) unsigned short u16x4;

#define AS1 __attribute__((address_space(1)))
#define AS3 __attribute__((address_space(3)))

// B=2, T=2048, C=1024, H=16, HD=64
#define Tn 2048
#define Cn 1024
#define Hn 16
#define HDn 64

struct FalseT { static constexpr bool value = false; };
struct TrueT  { static constexpr bool value = true;  };

static __device__ __forceinline__ u16 f2bf(float f) {
    unsigned int u = __float_as_uint(f);
    u += 0x7FFFu + ((u >> 16) & 1u);   // round-to-nearest-even
    return (u16)(u >> 16);
}

static __device__ __forceinline__ void ldlds16(const void* g, void* l) {
    __builtin_amdgcn_global_load_lds((const AS1 unsigned int*)g,
                                     (AS3 unsigned int*)l, 16, 0, 0);
}

// ---------------- fused prep: x->bf16 | Wqkv^T->bf16 | Wo^T->bf16 ----------------
__global__ void prep(const float* __restrict__ x, u16* __restrict__ xb,
                     const float* __restrict__ Wqkv, u16* __restrict__ wqkvt,
                     const float* __restrict__ Wo, u16* __restrict__ wot) {
    __shared__ float t[64][65];
    const int bx = blockIdx.x, tid = threadIdx.x;
    if (bx < 4096) {
        int i = bx * 256 + tid;
        float4v v = ((const float4v*)x)[i];
        u16x4 o;
        o.x = f2bf(v.x); o.y = f2bf(v.y); o.z = f2bf(v.z); o.w = f2bf(v.w);
        ((u16x4*)xb)[i] = o;
        return;
    }
    const float* in; u16* out; int R, Cc, r0, c0;
    if (bx < 4864) {
        int idx = bx - 4096;
        in = Wqkv; out = wqkvt; R = 1024; Cc = 3072;
        c0 = (idx % 48) * 64; r0 = (idx / 48) * 64;
    } else {
        int idx = bx - 4864;
        in = Wo; out = wot; R = 1024; Cc = 1024;
        c0 = (idx & 15) * 64; r0 = (idx >> 4) * 64;
    }
    int tx = tid & 63, ty = tid >> 6;
#pragma unroll
    for (int i = 0; i < 64; i += 4)
        t[ty + i][tx] = in[(long)(r0 + ty + i) * Cc + c0 + tx];
    __syncthreads();
#pragma unroll
    for (int i = 0; i < 64; i += 4)
        out[(long)(c0 + ty + i) * R + r0 + tx] = f2bf(t[tx][ty + i]);
}

// ---------------- m97-style GEMM: C[M][N] = A[M][K] * Bt[N][K]^T + bias ----------------
// MODE 0: coalesced bf16 out[M][N]; softmax scale folded into Q columns (n<1024);
//         V-blocks (n0>=2048) transpose their tile via LDS and write V^T to vout
//         directly (replaces the transpose_v kernel; qkvb's V third never stored).
// MODE 1: fp32 out[M][N].
template <int MODE>
__global__ __launch_bounds__(256, 3)
void gemm_bt(const u16* __restrict__ A, const u16* __restrict__ Bt,
             const float* __restrict__ bias,
             u16* __restrict__ o16, u16* __restrict__ vout,
             float* __restrict__ f_out,
             int M, int N, int K) {
    __shared__ __attribute__((aligned(16))) u16 S[8192];   // As[4096] | Bs[4096]
    u16* As = S;
    u16* Bs = S + 4096;
    const int tid = threadIdx.x;
    const int l = tid & 63;
    const int w = tid >> 6;
    const int wm = (w >> 1) * 64, wn = (w & 1) * 64;
    const long m0 = (long)blockIdx.x * 128, n0 = (long)blockIdx.y * 128;
    const int lm = l & 15, g = l >> 4;

    const int sr = tid >> 2;
    const int sc = (tid & 3) ^ ((tid >> 3) & 3);
    const u16* Ag = A + (m0 + sr) * K + sc * 8;
    const u16* Bg = Bt + (n0 + sr) * K + sc * 8;
    u16* Asl = As + tid * 8;
    u16* Bsl = Bs + tid * 8;

    const int x0 = (lm >> 1) & 3;

    f32x4 acc[4][4] = {};

    for (int k0 = 0; k0 < K; k0 += 32) {
        __syncthreads();
        ldlds16(Ag + k0, Asl);
        ldlds16(Ag + (long)64 * K + k0, Asl + 2048);
        ldlds16(Bg + k0, Bsl);
        ldlds16(Bg + (long)64 * K + k0, Bsl + 2048);
        __syncthreads();
        short8 af[4], bf[4];
#pragma unroll
        for (int mt = 0; mt < 4; ++mt)
            af[mt] = *(const short8*)(As + (wm + mt * 16 + lm) * 32 + ((g ^ x0) * 8));
#pragma unroll
        for (int nt = 0; nt < 4; ++nt)
            bf[nt] = *(const short8*)(Bs + (wn + nt * 16 + lm) * 32 + ((g ^ x0) * 8));
#pragma unroll
        for (int mt = 0; mt < 4; ++mt)
#pragma unroll
            for (int nt = 0; nt < 4; ++nt)
                acc[mt][nt] = __builtin_amdgcn_mfma_f32_16x16x32_bf16(
                    af[mt], bf[nt], acc[mt][nt], 0, 0, 0);
    }

    if (MODE == 0 && n0 >= 2048) {
        // ---- fused V^T emit: transpose 128x128 tile via 16KB LDS, 2 passes ----
        // tile covers t = t0..t0+127 of batch b, V-dims n0b..n0b+127 (= heads
        // n0b/64, n0b/64+1). Writes vout[((b*16+h)*64+d)*2048 + t], bf16,
        // bit-identical to the old qkvb-store + transpose_v path.
        const long b = m0 >> 11;
        const int t0 = (int)(m0 & 2047);
        const int n0b = (int)(n0 - 2048);
#pragma unroll
        for (int p = 0; p < 2; ++p) {
            __syncthreads();               // prior LDS reads (k-loop / pass p-1) done
            if ((w & 1) == p) {            // waves whose wn == p*64 hold this n-half
#pragma unroll
                for (int mt = 0; mt < 4; ++mt) {
                    const int colu = wm + mt * 16 + g * 4;   // m_local base (4-aligned)
#pragma unroll
                    for (int nt = 0; nt < 4; ++nt) {
                        const int row = nt * 16 + lm;        // n_local in 0..63
                        float bv = bias[n0 + p * 64 + row];
                        u16 tmp[4];
#pragma unroll
                        for (int r = 0; r < 4; ++r)
                            tmp[r] = f2bf(acc[mt][nt][r] + bv);
                        // XOR-swizzle columns by row (T2-style) to avoid 16-way write conflicts
                        *(u16x4*)(S + row * 128 + (colu ^ (lm << 3))) = *(const u16x4*)tmp;
                    }
                }
            }
            __syncthreads();
            {   // coalesced V^T store: 4 threads per n-row, 64B each along t
                const int nl = tid >> 2, mb = (tid & 3) * 32;
                const int ng = n0b + p * 64 + nl;
                u16* dst = vout + (((b * 16 + (ng >> 6)) * 64 + (ng & 63)) * (long)Tn) + t0;
#pragma unroll
                for (int j = 0; j < 4; ++j) {
                    const int c = mb + j * 8;
                    *(short8*)(dst + c) =
                        *(const short8*)(S + nl * 128 + (c ^ ((nl & 15) << 3)));
                }
            }
        }
        return;
    }

    const int r0 = (l >> 4) * 4;
#pragma unroll
    for (int mt = 0; mt < 4; ++mt) {
#pragma unroll
        for (int nt = 0; nt < 4; ++nt) {
            long n = n0 + wn + nt * 16 + lm;
            float bv = bias[n];
            // fold softmax scale (0.125*log2e) into Q columns at MODE 0
            float scq = (MODE == 0 && n < 1024) ? 0.18033688f : 1.0f;
#pragma unroll
            for (int r = 0; r < 4; ++r) {
                long m = m0 + wm + mt * 16 + r0 + r;
                float v = (acc[mt][nt][r] + bv) * scq;
                if (MODE == 0) o16[m * N + n] = f2bf(v);
                else           f_out[m * N + n] = v;
            }
        }
    }
}

// ---------------- 64x128-tile fp32-out GEMM (for Wo projection) ----------------
// M=4096,N=1024: 128^2 tiles gave 256 blocks = 1 block/CU = 1 wave/SIMD -> every
// staging drain fully exposed. 64x128 tiles -> 512 blocks = 2 blocks/CU.
__global__ __launch_bounds__(256, 3)
void gemm_bt64(const u16* __restrict__ A, const u16* __restrict__ Bt,
               const float* __restrict__ bias, float* __restrict__ f_out,
               int M, int N, int K) {
    __shared__ __attribute__((aligned(16))) u16 As[64 * 32];
    __shared__ __attribute__((aligned(16))) u16 Bs[128 * 32];
    const int tid = threadIdx.x;
    const int l = tid & 63;
    const int w = tid >> 6;
    const int wm = (w >> 1) * 32, wn = (w & 1) * 64;
    const long m0 = (long)blockIdx.x * 64, n0 = (long)blockIdx.y * 128;
    const int lm = l & 15, g = l >> 4;

    const int sr = tid >> 2;
    const int sc = (tid & 3) ^ ((tid >> 3) & 3);
    const u16* Ag = A + (m0 + sr) * K + sc * 8;
    const u16* Bg = Bt + (n0 + sr) * K + sc * 8;
    u16* Asl = As + tid * 8;
    u16* Bsl = Bs + tid * 8;

    const int x0 = (lm >> 1) & 3;

    f32x4 acc[2][4] = {};

    for (int k0 = 0; k0 < K; k0 += 32) {
        __syncthreads();
        ldlds16(Ag + k0, Asl);
        ldlds16(Bg + k0, Bsl);
        ldlds16(Bg + (long)64 * K + k0, Bsl + 2048);
        __syncthreads();
        short8 af[2], bf[4];
#pragma unroll
        for (int mt = 0; mt < 2; ++mt)
            af[mt] = *(const short8*)(As + (wm + mt * 16 + lm) * 32 + ((g ^ x0) * 8));
#pragma unroll
        for (int nt = 0; nt < 4; ++nt)
            bf[nt] = *(const short8*)(Bs + (wn + nt * 16 + lm) * 32 + ((g ^ x0) * 8));
#pragma unroll
        for (int mt = 0; mt < 2; ++mt)
#pragma unroll
            for (int nt = 0; nt < 4; ++nt)
                acc[mt][nt] = __builtin_amdgcn_mfma_f32_16x16x32_bf16(
                    af[mt], bf[nt], acc[mt][nt], 0, 0, 0);
    }

    const int r0 = g * 4;
#pragma unroll
    for (int mt = 0; mt < 2; ++mt) {
#pragma unroll
        for (int nt = 0; nt < 4; ++nt) {
            long n = n0 + wn + nt * 16 + lm;
            float bv = bias[n];
#pragma unroll
            for (int r = 0; r < 4; ++r) {
                long m = m0 + wm + mt * 16 + r0 + r;
                f_out[m * N + n] = acc[mt][nt][r] + bv;
            }
        }
    }
}

// ---------------- flash attention: S^T formulation, zero P round-trip ----------------
// R1 shape (proven 43.0us): 512 threads = 8 waves, 4-way q-split (mh) x 2-way
// s-split (sh). R2/R3's 2mh x 4sh reshape regressed (~25% stretch) despite halved
// bank conflicts -- LDS reads were not the critical path; reverted.
// Added: XCD-aware bijective block swizzle (512 = 8 x 64): each XCD residue class
// handles 4 (b,h) heads -> K/V panels L2-resident instead of refetched per XCD.
// Q pre-scaled by 0.125*log2e in gemm_bt<0>, so softmax inner loop is bare exp2.
// LDS 64 KB: Ks[2] 128x64 @0/8192, Vs[2] 64x128 @16384/24576 (u16 idx).
__global__ __launch_bounds__(512, 4)
void attn(const u16* __restrict__ qkv, const u16* __restrict__ Vt,
          u16* __restrict__ Y) {
    __shared__ __attribute__((aligned(16))) u16 S_lds[32768];

    // XCD swizzle: lin = hw linear block id; residue class (lin&7) -> 64 blocks
    // = bh in [4c, 4c+4) x px 0..15, all co-resident on one XCD.
    const int lin = blockIdx.x + (blockIdx.y << 4);
    const int s = (lin & 7) * 64 + (lin >> 3);
    const int px = s & 15;                 // 0..15
    const int bh = s >> 4;                 // 0..31
    const int tid = threadIdx.x, l = tid & 63, w = tid >> 6;   // w 0..7
    const int mh = w >> 1, sh = w & 1;
    const int lm = l & 15, g = l >> 4;
    const int lm7 = lm & 7;
    const int mh16 = mh * 16, sh64 = sh * 64, sh8 = sh * 8, g4 = g * 4;
    const int b = bh >> 4, h = bh & 15;

    const u16* Kp = qkv + (long)b * Tn * 3072 + 1024 + h * 64;
    const u16* Vp = Vt + (long)bh * HDn * Tn;

    // 512-thread staging: K 64 rows/round (2 rounds), V 32 rows/round (2 rounds)
    const int soffK = (tid >> 3) * 3072 + (((tid & 7) ^ ((tid >> 3) & 7)) * 8);
    const int soffV = (tid >> 4) * Tn + (((tid & 15) ^ ((tid >> 4) & 15)) * 8);

    auto prefetch = [&](int i, int buf) {
        u16* Kn = S_lds + buf * 8192;
        u16* Vn = S_lds + 16384 + buf * 8192;
        const u16* Kt = Kp + (long)i * 128 * 3072;
        const u16* Vg = Vp + i * 128;
#pragma unroll
        for (int j = 0; j < 2; ++j) {
            ldlds16(Kt + j * (64 * 3072) + soffK, Kn + j * 4096 + tid * 8);
            ldlds16(Vg + j * (32 * Tn) + soffV, Vn + j * 4096 + tid * 8);
        }
    };

    for (int job = 0; job < 2; ++job) {
        const int qt = job ? px : 31 - px;
        const u16* Qp = qkv + ((long)b * Tn + qt * 64) * 3072 + h * 64;

        // Q fragments (B-operand of S^T mfma): Q[q=mh16+lm][d=hh*32+g*8+j]
        short8 qa[2];
#pragma unroll
        for (int hh = 0; hh < 2; ++hh)
            qa[hh] = *(const short8*)(Qp + (mh16 + lm) * 3072 + hh * 32 + g * 8);

        f32x4 o_acc[4] = {};          // O^T[d=dt*16+g4+r][q=mh16+lm]
        float lsum = 0.f;
        const int qrow = qt * 64 + mh16 + lm;

        prefetch(0, 0);
        __syncthreads();

        auto body = [&](int buf, int sbase, auto diag_c) {
            constexpr bool DIAG = decltype(diag_c)::value;
            const u16* Kc = S_lds + buf * 8192;
            const u16* Vc = S_lds + 16384 + buf * 8192;
            // S^T = K * Q^T : 1 q-tile x 4 s-tiles, k=64
            f32x4 st[4];
#pragma unroll
            for (int nt = 0; nt < 4; ++nt)
                st[nt] = (f32x4){0.f, 0.f, 0.f, 0.f};
#pragma unroll
            for (int nt = 0; nt < 4; ++nt)
#pragma unroll
                for (int hh = 0; hh < 2; ++hh) {
                    short8 kf = *(const short8*)(Kc + (sh64 + nt * 16 + lm) * 64 +
                                                 (((hh * 4 + g) ^ lm7) * 8));
                    st[nt] = __builtin_amdgcn_mfma_f32_16x16x32_bf16(kf, qa[hh], st[nt], 0, 0, 0);
                }
            // exp2 + mask + pack to bf16 B-fragments (P^T stays in registers)
            short4v pb[4];
#pragma unroll
            for (int nt = 0; nt < 4; ++nt) {
                const int scolb = sbase + sh64 + nt * 16 + g4;
#pragma unroll
                for (int r = 0; r < 4; ++r) {
                    float xx = st[nt][r];
                    if (DIAG && scolb + r > qrow) xx = -1e30f;
                    float p = exp2f(xx);
                    lsum += p;
                    pb[nt][r] = (short)(__float_as_uint(p) >> 16);
                }
            }
            // O^T += V^T * P^T : per (s-16-chunk, d-tile) one 16x16x16 MFMA
#pragma unroll
            for (int nt = 0; nt < 4; ++nt) {
                const int vcol = (((sh8 + nt * 2 + (g >> 1)) ^ lm) * 8) + (g & 1) * 4;
#pragma unroll
                for (int dt = 0; dt < 4; ++dt) {
                    short4v vf = *(const short4v*)(Vc + (dt * 16 + lm) * 128 + vcol);
                    o_acc[dt] = __builtin_amdgcn_mfma_f32_16x16x16bf16_1k(vf, pb[nt], o_acc[dt], 0, 0, 0);
                }
            }
        };

        const int n = (qt >> 1) + 1;     // 128-col iterations; last is DIAG
        if (n == 1) {
            body(0, 0, TrueT{});
        } else {
            int i = 0;
            for (; i + 2 <= n - 1; i += 2) {
                prefetch(i + 1, 1); body(0, i * 128, FalseT{}); __syncthreads();
                prefetch(i + 2, 0); body(1, (i + 1) * 128, FalseT{}); __syncthreads();
            }
            if (i == n - 2) {
                prefetch(n - 1, 1); body(0, i * 128, FalseT{}); __syncthreads();
                body(1, (n - 1) * 128, TrueT{});
            } else {  // i == n-1
                body(0, i * 128, TrueT{});
            }
        }

        // rowsum: sum across the 4 quads holding the same q=lm
        lsum += __shfl_xor(lsum, 16, 64);
        lsum += __shfl_xor(lsum, 32, 64);

        // ---- epilogue: cross-sh reduce + transpose via padded f32 LDS ----
        __syncthreads();
        float* Ytf = (float*)S_lds;               // [64][68] f32 (17408 B)
        float* redl = (float*)(S_lds + 8704);     // 64 f32

        if (sh == 1) {
            const int q = mh16 + lm;
#pragma unroll
            for (int dt = 0; dt < 4; ++dt)
                *(f32x4*)(Ytf + q * 68 + dt * 16 + g4) = o_acc[dt];
            if (g == 0) redl[q] = lsum;
        }
        __syncthreads();
        if (sh == 0) {
            const int q = mh16 + lm;
            float inv = 1.0f / (lsum + redl[q]);
#pragma unroll
            for (int dt = 0; dt < 4; ++dt) {
                f32x4 t = *(const f32x4*)(Ytf + q * 68 + dt * 16 + g4);
                t += o_acc[dt];
                t *= inv;
                *(f32x4*)(Ytf + q * 68 + dt * 16 + g4) = t;
            }
        }
        __syncthreads();
        {   // coalesced store: 8 threads per q-row, 8 bf16 each
            const int q = tid >> 3, dseg = (tid & 7) * 8;
            long base = ((long)b * Tn + qt * 64 + q) * Cn + h * HDn + dseg;
            u16 tmp[8];
#pragma unroll
            for (int j = 0; j < 8; ++j)
                tmp[j] = f2bf(Ytf[q * 68 + dseg + j]);
            *(short8*)(Y + base) = *(const short8*)tmp;
        }
        __syncthreads();   // LDS reads done before next job restages
    }
}

extern "C" void kernel_launch(void* const* d_in, const int* in_sizes, int n_in,
                              void* d_out, int out_size, void* d_ws, size_t ws_size,
                              hipStream_t stream) {
    const float* x    = (const float*)d_in[0];
    const float* Wqkv = (const float*)d_in[1];
    const float* bqkv = (const float*)d_in[2];
    const float* Wo   = (const float*)d_in[3];
    const float* bo   = (const float*)d_in[4];
    float* out = (float*)d_out;

    u16* xb    = (u16*)d_ws;          // 4M u16 : x bf16
    u16* wqkvt = xb + 4194304;        // 3M : Wqkv^T
    u16* wot   = wqkvt + 3145728;     // 1M : Wo^T
    u16* qkvb  = wot + 1048576;       // 12M : qkv [b,t,3C] bf16 (Q pre-scaled; V third unused)
    u16* vtb   = qkvb + 12582912;     // 4M : V^T [b,h,d,t] (written by gemm_bt<0>)
    u16* yb    = vtb + 4194304;       // 4M : attn out [b,t,c]

    prep<<<5120, 256, 0, stream>>>(x, xb, Wqkv, wqkvt, Wo, wot);
    gemm_bt<0><<<dim3(32, 24), 256, 0, stream>>>(xb, wqkvt, bqkv, qkvb, vtb,
                                                 nullptr, 4096, 3072, 1024);
    attn<<<dim3(16, 32), 512, 0, stream>>>(qkvb, vtb, yb);
    gemm_bt64<<<dim3(64, 8), 256, 0, stream>>>(yb, wot, bo, out, 4096, 1024, 1024);
}

// Round 5
// 174.915 us; speedup vs baseline: 1.1048x; 1.0090x over previous
//
#include <hip/hip_runtime.h>

typedef unsigned short u16;
typedef __attribute__((ext_vector_type(8))) short short8;
typedef __attribute__((ext_vector_type(4))) short short4v;
typedef __attribute__((ext_vector_type(4))) float f32x4;
typedef __attribute__((ext_vector_type(4))) float float4v;
typedef __attribute__((ext_vector_type(4))) unsigned short u16x4;
typedef __attribute__((ext_vector_type(2))) unsigned int uint2v;

#define AS1 __attribute__((address_space(1)))
#define AS3 __attribute__((address_space(3)))

// B=2, T=2048, C=1024, H=16, HD=64
#define Tn 2048
#define Cn 1024
#define Hn 16
#define HDn 64

struct FalseT { static constexpr bool value = false; };
struct TrueT  { static constexpr bool value = true;  };

static __device__ __forceinline__ u16 f2bf(float f) {
    unsigned int u = __float_as_uint(f);
    u += 0x7FFFu + ((u >> 16) & 1u);   // round-to-nearest-even
    return (u16)(u >> 16);
}

static __device__ __forceinline__ void ldlds16(const void* g, void* l) {
    __builtin_amdgcn_global_load_lds((const AS1 unsigned int*)g,
                                     (AS3 unsigned int*)l, 16, 0, 0);
}

// ---------------- fused prep: x->bf16 | Wqkv^T->bf16 | Wo^T->bf16 ----------------
__global__ void prep(const float* __restrict__ x, u16* __restrict__ xb,
                     const float* __restrict__ Wqkv, u16* __restrict__ wqkvt,
                     const float* __restrict__ Wo, u16* __restrict__ wot) {
    __shared__ float t[64][65];
    const int bx = blockIdx.x, tid = threadIdx.x;
    if (bx < 4096) {
        int i = bx * 256 + tid;
        float4v v = ((const float4v*)x)[i];
        u16x4 o;
        o.x = f2bf(v.x); o.y = f2bf(v.y); o.z = f2bf(v.z); o.w = f2bf(v.w);
        ((u16x4*)xb)[i] = o;
        return;
    }
    const float* in; u16* out; int R, Cc, r0, c0;
    if (bx < 4864) {
        int idx = bx - 4096;
        in = Wqkv; out = wqkvt; R = 1024; Cc = 3072;
        c0 = (idx % 48) * 64; r0 = (idx / 48) * 64;
    } else {
        int idx = bx - 4864;
        in = Wo; out = wot; R = 1024; Cc = 1024;
        c0 = (idx & 15) * 64; r0 = (idx >> 4) * 64;
    }
    int tx = tid & 63, ty = tid >> 6;
#pragma unroll
    for (int i = 0; i < 64; i += 4)
        t[ty + i][tx] = in[(long)(r0 + ty + i) * Cc + c0 + tx];
    __syncthreads();
#pragma unroll
    for (int i = 0; i < 64; i += 4)
        out[(long)(c0 + ty + i) * R + r0 + tx] = f2bf(t[tx][ty + i]);
}

// ---------------- m97-style GEMM: C[M][N] = A[M][K] * Bt[N][K]^T + bias ----------------
// MODE 0: coalesced bf16 out[M][N]; softmax scale folded into Q columns (n<1024);
//         V-blocks (n0>=2048) transpose their tile via LDS and write V^T to vout
//         directly (replaces the transpose_v kernel; qkvb's V third never stored).
// MODE 1: fp32 out[M][N].
template <int MODE>
__global__ __launch_bounds__(256, 3)
void gemm_bt(const u16* __restrict__ A, const u16* __restrict__ Bt,
             const float* __restrict__ bias,
             u16* __restrict__ o16, u16* __restrict__ vout,
             float* __restrict__ f_out,
             int M, int N, int K) {
    __shared__ __attribute__((aligned(16))) u16 S[8192];   // As[4096] | Bs[4096]
    u16* As = S;
    u16* Bs = S + 4096;
    const int tid = threadIdx.x;
    const int l = tid & 63;
    const int w = tid >> 6;
    const int wm = (w >> 1) * 64, wn = (w & 1) * 64;
    const long m0 = (long)blockIdx.x * 128, n0 = (long)blockIdx.y * 128;
    const int lm = l & 15, g = l >> 4;

    const int sr = tid >> 2;
    const int sc = (tid & 3) ^ ((tid >> 3) & 3);
    const u16* Ag = A + (m0 + sr) * K + sc * 8;
    const u16* Bg = Bt + (n0 + sr) * K + sc * 8;
    u16* Asl = As + tid * 8;
    u16* Bsl = Bs + tid * 8;

    const int x0 = (lm >> 1) & 3;

    f32x4 acc[4][4] = {};

    for (int k0 = 0; k0 < K; k0 += 32) {
        __syncthreads();
        ldlds16(Ag + k0, Asl);
        ldlds16(Ag + (long)64 * K + k0, Asl + 2048);
        ldlds16(Bg + k0, Bsl);
        ldlds16(Bg + (long)64 * K + k0, Bsl + 2048);
        __syncthreads();
        short8 af[4], bf[4];
#pragma unroll
        for (int mt = 0; mt < 4; ++mt)
            af[mt] = *(const short8*)(As + (wm + mt * 16 + lm) * 32 + ((g ^ x0) * 8));
#pragma unroll
        for (int nt = 0; nt < 4; ++nt)
            bf[nt] = *(const short8*)(Bs + (wn + nt * 16 + lm) * 32 + ((g ^ x0) * 8));
#pragma unroll
        for (int mt = 0; mt < 4; ++mt)
#pragma unroll
            for (int nt = 0; nt < 4; ++nt)
                acc[mt][nt] = __builtin_amdgcn_mfma_f32_16x16x32_bf16(
                    af[mt], bf[nt], acc[mt][nt], 0, 0, 0);
    }

    if (MODE == 0 && n0 >= 2048) {
        // ---- fused V^T emit: transpose 128x128 tile via 16KB LDS, 2 passes ----
        const long b = m0 >> 11;
        const int t0 = (int)(m0 & 2047);
        const int n0b = (int)(n0 - 2048);
#pragma unroll
        for (int p = 0; p < 2; ++p) {
            __syncthreads();               // prior LDS reads (k-loop / pass p-1) done
            if ((w & 1) == p) {            // waves whose wn == p*64 hold this n-half
#pragma unroll
                for (int mt = 0; mt < 4; ++mt) {
                    const int colu = wm + mt * 16 + g * 4;   // m_local base (4-aligned)
#pragma unroll
                    for (int nt = 0; nt < 4; ++nt) {
                        const int row = nt * 16 + lm;        // n_local in 0..63
                        float bv = bias[n0 + p * 64 + row];
                        u16 tmp[4];
#pragma unroll
                        for (int r = 0; r < 4; ++r)
                            tmp[r] = f2bf(acc[mt][nt][r] + bv);
                        // XOR-swizzle columns by row (T2-style) to avoid 16-way write conflicts
                        *(u16x4*)(S + row * 128 + (colu ^ (lm << 3))) = *(const u16x4*)tmp;
                    }
                }
            }
            __syncthreads();
            {   // coalesced V^T store: 4 threads per n-row, 64B each along t
                const int nl = tid >> 2, mb = (tid & 3) * 32;
                const int ng = n0b + p * 64 + nl;
                u16* dst = vout + (((b * 16 + (ng >> 6)) * 64 + (ng & 63)) * (long)Tn) + t0;
#pragma unroll
                for (int j = 0; j < 4; ++j) {
                    const int c = mb + j * 8;
                    *(short8*)(dst + c) =
                        *(const short8*)(S + nl * 128 + (c ^ ((nl & 15) << 3)));
                }
            }
        }
        return;
    }

    const int r0 = (l >> 4) * 4;
#pragma unroll
    for (int mt = 0; mt < 4; ++mt) {
#pragma unroll
        for (int nt = 0; nt < 4; ++nt) {
            long n = n0 + wn + nt * 16 + lm;
            float bv = bias[n];
            // fold softmax scale (0.125*log2e) into Q columns at MODE 0
            float scq = (MODE == 0 && n < 1024) ? 0.18033688f : 1.0f;
#pragma unroll
            for (int r = 0; r < 4; ++r) {
                long m = m0 + wm + mt * 16 + r0 + r;
                float v = (acc[mt][nt][r] + bv) * scq;
                if (MODE == 0) o16[m * N + n] = f2bf(v);
                else           f_out[m * N + n] = v;
            }
        }
    }
}

// ---------------- 64x128-tile fp32-out GEMM (for Wo projection) ----------------
__global__ __launch_bounds__(256, 3)
void gemm_bt64(const u16* __restrict__ A, const u16* __restrict__ Bt,
               const float* __restrict__ bias, float* __restrict__ f_out,
               int M, int N, int K) {
    __shared__ __attribute__((aligned(16))) u16 As[64 * 32];
    __shared__ __attribute__((aligned(16))) u16 Bs[128 * 32];
    const int tid = threadIdx.x;
    const int l = tid & 63;
    const int w = tid >> 6;
    const int wm = (w >> 1) * 32, wn = (w & 1) * 64;
    const long m0 = (long)blockIdx.x * 64, n0 = (long)blockIdx.y * 128;
    const int lm = l & 15, g = l >> 4;

    const int sr = tid >> 2;
    const int sc = (tid & 3) ^ ((tid >> 3) & 3);
    const u16* Ag = A + (m0 + sr) * K + sc * 8;
    const u16* Bg = Bt + (n0 + sr) * K + sc * 8;
    u16* Asl = As + tid * 8;
    u16* Bsl = Bs + tid * 8;

    const int x0 = (lm >> 1) & 3;

    f32x4 acc[2][4] = {};

    for (int k0 = 0; k0 < K; k0 += 32) {
        __syncthreads();
        ldlds16(Ag + k0, Asl);
        ldlds16(Bg + k0, Bsl);
        ldlds16(Bg + (long)64 * K + k0, Bsl + 2048);
        __syncthreads();
        short8 af[2], bf[4];
#pragma unroll
        for (int mt = 0; mt < 2; ++mt)
            af[mt] = *(const short8*)(As + (wm + mt * 16 + lm) * 32 + ((g ^ x0) * 8));
#pragma unroll
        for (int nt = 0; nt < 4; ++nt)
            bf[nt] = *(const short8*)(Bs + (wn + nt * 16 + lm) * 32 + ((g ^ x0) * 8));
#pragma unroll
        for (int mt = 0; mt < 2; ++mt)
#pragma unroll
            for (int nt = 0; nt < 4; ++nt)
                acc[mt][nt] = __builtin_amdgcn_mfma_f32_16x16x32_bf16(
                    af[mt], bf[nt], acc[mt][nt], 0, 0, 0);
    }

    const int r0 = g * 4;
#pragma unroll
    for (int mt = 0; mt < 2; ++mt) {
#pragma unroll
        for (int nt = 0; nt < 4; ++nt) {
            long n = n0 + wn + nt * 16 + lm;
            float bv = bias[n];
#pragma unroll
            for (int r = 0; r < 4; ++r) {
                long m = m0 + wm + mt * 16 + r0 + r;
                f_out[m * N + n] = acc[mt][nt][r] + bv;
            }
        }
    }
}

// ---------------- flash attention: S^T formulation, zero P round-trip ----------------
// R1 shape (proven): 512 threads = 8 waves, 4-way q-split (mh) x 2-way s-split (sh).
// XCD-aware bijective block swizzle: K/V panels L2-resident (FETCH 91->12MB, R4).
// VALU-diet round: (1) rowsum folded into matrix pipe via all-ones MFMA (o_sum);
// kills 16 v_add + 2 shfl per body; denominator now sums bf16 P, consistent with
// PV numerator. (2) explicit v_perm bf16 packing (8 perms vs ~24 shift/inserts).
// (3) s_setprio(1) around MFMA clusters (T5). launch_bounds(512,2): 128-VGPR cap
// (at (512,4)'s 64-cap the +8 regs would re-trigger the R2 spill); occupancy is
// LDS-bound at 2 blocks/CU either way.
// Q pre-scaled by 0.125*log2e in gemm_bt<0>, so softmax inner loop is bare exp2.
// LDS 64 KB: Ks[2] 128x64 @0/8192, Vs[2] 64x128 @16384/24576 (u16 idx).
__global__ __launch_bounds__(512, 2)
void attn(const u16* __restrict__ qkv, const u16* __restrict__ Vt,
          u16* __restrict__ Y) {
    __shared__ __attribute__((aligned(16))) u16 S_lds[32768];

    // XCD swizzle: lin = hw linear block id; residue class (lin&7) -> 64 blocks
    // = bh in [4c, 4c+4) x px 0..15, all co-resident on one XCD.
    const int lin = blockIdx.x + (blockIdx.y << 4);
    const int s = (lin & 7) * 64 + (lin >> 3);
    const int px = s & 15;                 // 0..15
    const int bh = s >> 4;                 // 0..31
    const int tid = threadIdx.x, l = tid & 63, w = tid >> 6;   // w 0..7
    const int mh = w >> 1, sh = w & 1;
    const int lm = l & 15, g = l >> 4;
    const int lm7 = lm & 7;
    const int mh16 = mh * 16, sh64 = sh * 64, sh8 = sh * 8, g4 = g * 4;
    const int b = bh >> 4, h = bh & 15;

    const short4v ones = {(short)0x3F80, (short)0x3F80, (short)0x3F80, (short)0x3F80};

    const u16* Kp = qkv + (long)b * Tn * 3072 + 1024 + h * 64;
    const u16* Vp = Vt + (long)bh * HDn * Tn;

    // 512-thread staging: K 64 rows/round (2 rounds), V 32 rows/round (2 rounds)
    const int soffK = (tid >> 3) * 3072 + (((tid & 7) ^ ((tid >> 3) & 7)) * 8);
    const int soffV = (tid >> 4) * Tn + (((tid & 15) ^ ((tid >> 4) & 15)) * 8);

    auto prefetch = [&](int i, int buf) {
        u16* Kn = S_lds + buf * 8192;
        u16* Vn = S_lds + 16384 + buf * 8192;
        const u16* Kt = Kp + (long)i * 128 * 3072;
        const u16* Vg = Vp + i * 128;
#pragma unroll
        for (int j = 0; j < 2; ++j) {
            ldlds16(Kt + j * (64 * 3072) + soffK, Kn + j * 4096 + tid * 8);
            ldlds16(Vg + j * (32 * Tn) + soffV, Vn + j * 4096 + tid * 8);
        }
    };

    for (int job = 0; job < 2; ++job) {
        const int qt = job ? px : 31 - px;
        const u16* Qp = qkv + ((long)b * Tn + qt * 64) * 3072 + h * 64;

        // Q fragments (B-operand of S^T mfma): Q[q=mh16+lm][d=hh*32+g*8+j]
        short8 qa[2];
#pragma unroll
        for (int hh = 0; hh < 2; ++hh)
            qa[hh] = *(const short8*)(Qp + (mh16 + lm) * 3072 + hh * 32 + g * 8);

        f32x4 o_acc[4] = {};          // O^T[d=dt*16+g4+r][q=mh16+lm]
        f32x4 o_sum = {};             // all-ones MFMA rowsum: each entry = sum_s P[s][q=lm]
        const int qrow = qt * 64 + mh16 + lm;

        prefetch(0, 0);
        __syncthreads();

        auto body = [&](int buf, int sbase, auto diag_c) {
            constexpr bool DIAG = decltype(diag_c)::value;
            const u16* Kc = S_lds + buf * 8192;
            const u16* Vc = S_lds + 16384 + buf * 8192;
            // S^T = K * Q^T : 1 q-tile x 4 s-tiles, k=64
            f32x4 st[4];
#pragma unroll
            for (int nt = 0; nt < 4; ++nt)
                st[nt] = (f32x4){0.f, 0.f, 0.f, 0.f};
            __builtin_amdgcn_s_setprio(1);
#pragma unroll
            for (int nt = 0; nt < 4; ++nt)
#pragma unroll
                for (int hh = 0; hh < 2; ++hh) {
                    short8 kf = *(const short8*)(Kc + (sh64 + nt * 16 + lm) * 64 +
                                                 (((hh * 4 + g) ^ lm7) * 8));
                    st[nt] = __builtin_amdgcn_mfma_f32_16x16x32_bf16(kf, qa[hh], st[nt], 0, 0, 0);
                }
            __builtin_amdgcn_s_setprio(0);
            // exp2 + mask + v_perm pack to bf16 B-fragments (P^T stays in registers)
            short4v pb[4];
#pragma unroll
            for (int nt = 0; nt < 4; ++nt) {
                const int scolb = sbase + sh64 + nt * 16 + g4;
                float p[4];
#pragma unroll
                for (int r = 0; r < 4; ++r) {
                    float xx = st[nt][r];
                    if (DIAG && scolb + r > qrow) xx = -1e30f;
                    p[r] = exp2f(xx);
                }
                // [bf16(p0) | bf16(p1)<<16], [bf16(p2) | bf16(p3)<<16] (truncation)
                uint2v u;
                u.x = __builtin_amdgcn_perm(__float_as_uint(p[1]), __float_as_uint(p[0]), 0x07060302u);
                u.y = __builtin_amdgcn_perm(__float_as_uint(p[3]), __float_as_uint(p[2]), 0x07060302u);
                pb[nt] = __builtin_bit_cast(short4v, u);
            }
            // O^T += V^T * P^T ; rowsum += ones * P^T (matrix-pipe rowsum)
            __builtin_amdgcn_s_setprio(1);
#pragma unroll
            for (int nt = 0; nt < 4; ++nt) {
                const int vcol = (((sh8 + nt * 2 + (g >> 1)) ^ lm) * 8) + (g & 1) * 4;
                o_sum = __builtin_amdgcn_mfma_f32_16x16x16bf16_1k(ones, pb[nt], o_sum, 0, 0, 0);
#pragma unroll
                for (int dt = 0; dt < 4; ++dt) {
                    short4v vf = *(const short4v*)(Vc + (dt * 16 + lm) * 128 + vcol);
                    o_acc[dt] = __builtin_amdgcn_mfma_f32_16x16x16bf16_1k(vf, pb[nt], o_acc[dt], 0, 0, 0);
                }
            }
            __builtin_amdgcn_s_setprio(0);
        };

        const int n = (qt >> 1) + 1;     // 128-col iterations; last is DIAG
        if (n == 1) {
            body(0, 0, TrueT{});
        } else {
            int i = 0;
            for (; i + 2 <= n - 1; i += 2) {
                prefetch(i + 1, 1); body(0, i * 128, FalseT{}); __syncthreads();
                prefetch(i + 2, 0); body(1, (i + 1) * 128, FalseT{}); __syncthreads();
            }
            if (i == n - 2) {
                prefetch(n - 1, 1); body(0, i * 128, FalseT{}); __syncthreads();
                body(1, (n - 1) * 128, TrueT{});
            } else {  // i == n-1
                body(0, i * 128, TrueT{});
            }
        }

        // per-lane rowsum for q=lm over this wave's s-half (all o_sum entries equal)
        const float lsum = o_sum[0];

        // ---- epilogue: cross-sh reduce + transpose via padded f32 LDS ----
        __syncthreads();
        float* Ytf = (float*)S_lds;               // [64][68] f32 (17408 B)
        float* redl = (float*)(S_lds + 8704);     // 64 f32

        if (sh == 1) {
            const int q = mh16 + lm;
#pragma unroll
            for (int dt = 0; dt < 4; ++dt)
                *(f32x4*)(Ytf + q * 68 + dt * 16 + g4) = o_acc[dt];
            if (g == 0) redl[q] = lsum;
        }
        __syncthreads();
        if (sh == 0) {
            const int q = mh16 + lm;
            float inv = 1.0f / (lsum + redl[q]);
#pragma unroll
            for (int dt = 0; dt < 4; ++dt) {
                f32x4 t = *(const f32x4*)(Ytf + q * 68 + dt * 16 + g4);
                t += o_acc[dt];
                t *= inv;
                *(f32x4*)(Ytf + q * 68 + dt * 16 + g4) = t;
            }
        }
        __syncthreads();
        {   // coalesced store: 8 threads per q-row, 8 bf16 each
            const int q = tid >> 3, dseg = (tid & 7) * 8;
            long base = ((long)b * Tn + qt * 64 + q) * Cn + h * HDn + dseg;
            u16 tmp[8];
#pragma unroll
            for (int j = 0; j < 8; ++j)
                tmp[j] = f2bf(Ytf[q * 68 + dseg + j]);
            *(short8*)(Y + base) = *(const short8*)tmp;
        }
        __syncthreads();   // LDS reads done before next job restages
    }
}

extern "C" void kernel_launch(void* const* d_in, const int* in_sizes, int n_in,
                              void* d_out, int out_size, void* d_ws, size_t ws_size,
                              hipStream_t stream) {
    const float* x    = (const float*)d_in[0];
    const float* Wqkv = (const float*)d_in[1];
    const float* bqkv = (const float*)d_in[2];
    const float* Wo   = (const float*)d_in[3];
    const float* bo   = (const float*)d_in[4];
    float* out = (float*)d_out;

    u16* xb    = (u16*)d_ws;          // 4M u16 : x bf16
    u16* wqkvt = xb + 4194304;        // 3M : Wqkv^T
    u16* wot   = wqkvt + 3145728;     // 1M : Wo^T
    u16* qkvb  = wot + 1048576;       // 12M : qkv [b,t,3C] bf16 (Q pre-scaled; V third unused)
    u16* vtb   = qkvb + 12582912;     // 4M : V^T [b,h,d,t] (written by gemm_bt<0>)
    u16* yb    = vtb + 4194304;       // 4M : attn out [b,t,c]

    prep<<<5120, 256, 0, stream>>>(x, xb, Wqkv, wqkvt, Wo, wot);
    gemm_bt<0><<<dim3(32, 24), 256, 0, stream>>>(xb, wqkvt, bqkv, qkvb, vtb,
                                                 nullptr, 4096, 3072, 1024);
    attn<<<dim3(16, 32), 512, 0, stream>>>(qkvb, vtb, yb);
    gemm_bt64<<<dim3(64, 8), 256, 0, stream>>>(yb, wot, bo, out, 4096, 1024, 1024);
}

// Round 6
// 172.634 us; speedup vs baseline: 1.1194x; 1.0132x over previous
//
#include <hip/hip_runtime.h>

typedef unsigned short u16;
typedef __attribute__((ext_vector_type(8))) short short8;
typedef __attribute__((ext_vector_type(4))) short short4v;
typedef __attribute__((ext_vector_type(4))) float f32x4;
typedef __attribute__((ext_vector_type(4))) float float4v;
typedef __attribute__((ext_vector_type(4))) unsigned short u16x4;

#define AS1 __attribute__((address_space(1)))
#define AS3 __attribute__((address_space(3)))

// B=2, T=2048, C=1024, H=16, HD=64
#define Tn 2048
#define Cn 1024
#define Hn 16
#define HDn 64

struct FalseT { static constexpr bool value = false; };
struct TrueT  { static constexpr bool value = true;  };

static __device__ __forceinline__ u16 f2bf(float f) {
    unsigned int u = __float_as_uint(f);
    u += 0x7FFFu + ((u >> 16) & 1u);   // round-to-nearest-even
    return (u16)(u >> 16);
}

static __device__ __forceinline__ void ldlds16(const void* g, void* l) {
    __builtin_amdgcn_global_load_lds((const AS1 unsigned int*)g,
                                     (AS3 unsigned int*)l, 16, 0, 0);
}

// ---------------- fused prep: x->bf16 | Wqkv^T->bf16 | Wo^T->bf16 ----------------
__global__ void prep(const float* __restrict__ x, u16* __restrict__ xb,
                     const float* __restrict__ Wqkv, u16* __restrict__ wqkvt,
                     const float* __restrict__ Wo, u16* __restrict__ wot) {
    __shared__ float t[64][65];
    const int bx = blockIdx.x, tid = threadIdx.x;
    if (bx < 4096) {
        int i = bx * 256 + tid;
        float4v v = ((const float4v*)x)[i];
        u16x4 o;
        o.x = f2bf(v.x); o.y = f2bf(v.y); o.z = f2bf(v.z); o.w = f2bf(v.w);
        ((u16x4*)xb)[i] = o;
        return;
    }
    const float* in; u16* out; int R, Cc, r0, c0;
    if (bx < 4864) {
        int idx = bx - 4096;
        in = Wqkv; out = wqkvt; R = 1024; Cc = 3072;
        c0 = (idx % 48) * 64; r0 = (idx / 48) * 64;
    } else {
        int idx = bx - 4864;
        in = Wo; out = wot; R = 1024; Cc = 1024;
        c0 = (idx & 15) * 64; r0 = (idx >> 4) * 64;
    }
    int tx = tid & 63, ty = tid >> 6;
#pragma unroll
    for (int i = 0; i < 64; i += 4)
        t[ty + i][tx] = in[(long)(r0 + ty + i) * Cc + c0 + tx];
    __syncthreads();
#pragma unroll
    for (int i = 0; i < 64; i += 4)
        out[(long)(c0 + ty + i) * R + r0 + tx] = f2bf(t[tx][ty + i]);
}

// ---------------- m97-style GEMM, 512-thread variant ----------------
// 128x128 tile, 8 waves (4 wm x 2 wn), per-wave 32x64 output, acc[2][4].
// Same LDS layout/swizzle as the proven 256-thread version; staging is now one
// ldlds16 per thread per operand (512 x 8 u16 = full 128x32 tile).
// launch_bounds(512,3): session evidence (R2/R5) says 2nd arg = blocks/CU ->
// VGPR cap ~85 at 3 blocks/CU = 24 waves/CU (was 12 at 256 thr).
// MODE 0: bf16 out; softmax scale folded into Q cols (n<1024); V-blocks
// (n0>=2048) transpose via LDS and emit V^T directly.
template <int MODE>
__global__ __launch_bounds__(512, 3)
void gemm_bt(const u16* __restrict__ A, const u16* __restrict__ Bt,
             const float* __restrict__ bias,
             u16* __restrict__ o16, u16* __restrict__ vout,
             float* __restrict__ f_out,
             int M, int N, int K) {
    __shared__ __attribute__((aligned(16))) u16 S[8192];   // As[4096] | Bs[4096]
    u16* As = S;
    u16* Bs = S + 4096;
    const int tid = threadIdx.x;          // 0..511
    const int l = tid & 63;
    const int w = tid >> 6;               // 0..7
    const int wm = (w >> 1) * 32, wn = (w & 1) * 64;
    const long m0 = (long)blockIdx.x * 128, n0 = (long)blockIdx.y * 128;
    const int lm = l & 15, g = l >> 4;

    const int sr = tid >> 2;                       // 0..127
    const int sc = (tid & 3) ^ ((tid >> 3) & 3);
    const u16* Ag = A + (m0 + sr) * K + sc * 8;
    const u16* Bg = Bt + (n0 + sr) * K + sc * 8;
    u16* Asl = As + tid * 8;
    u16* Bsl = Bs + tid * 8;

    const int x0 = (lm >> 1) & 3;

    f32x4 acc[2][4] = {};

    for (int k0 = 0; k0 < K; k0 += 32) {
        __syncthreads();
        ldlds16(Ag + k0, Asl);
        ldlds16(Bg + k0, Bsl);
        __syncthreads();
        short8 af[2], bf[4];
#pragma unroll
        for (int mt = 0; mt < 2; ++mt)
            af[mt] = *(const short8*)(As + (wm + mt * 16 + lm) * 32 + ((g ^ x0) * 8));
#pragma unroll
        for (int nt = 0; nt < 4; ++nt)
            bf[nt] = *(const short8*)(Bs + (wn + nt * 16 + lm) * 32 + ((g ^ x0) * 8));
#pragma unroll
        for (int mt = 0; mt < 2; ++mt)
#pragma unroll
            for (int nt = 0; nt < 4; ++nt)
                acc[mt][nt] = __builtin_amdgcn_mfma_f32_16x16x32_bf16(
                    af[mt], bf[nt], acc[mt][nt], 0, 0, 0);
    }

    if (MODE == 0 && n0 >= 2048) {
        // ---- fused V^T emit: transpose 128x128 tile via 16KB LDS, 2 passes ----
        const long b = m0 >> 11;
        const int t0 = (int)(m0 & 2047);
        const int n0b = (int)(n0 - 2048);
#pragma unroll
        for (int p = 0; p < 2; ++p) {
            __syncthreads();               // prior LDS reads done
            if ((w & 1) == p) {            // 4 waves with wn == p*64 hold this n-half
#pragma unroll
                for (int mt = 0; mt < 2; ++mt) {
                    const int colu = wm + mt * 16 + g * 4;   // m_local base (4-aligned)
#pragma unroll
                    for (int nt = 0; nt < 4; ++nt) {
                        const int row = nt * 16 + lm;        // n_local in 0..63
                        float bv = bias[n0 + p * 64 + row];
                        u16 tmp[4];
#pragma unroll
                        for (int r = 0; r < 4; ++r)
                            tmp[r] = f2bf(acc[mt][nt][r] + bv);
                        // XOR-swizzle columns by row to avoid write conflicts
                        *(u16x4*)(S + row * 128 + (colu ^ (lm << 3))) = *(const u16x4*)tmp;
                    }
                }
            }
            __syncthreads();
            {   // coalesced V^T store: 8 threads per n-row, 16 u16 each along t
                const int nl = tid >> 3, mb = (tid & 7) * 16;
                const int ng = n0b + p * 64 + nl;
                u16* dst = vout + (((b * 16 + (ng >> 6)) * 64 + (ng & 63)) * (long)Tn) + t0;
#pragma unroll
                for (int j = 0; j < 2; ++j) {
                    const int c = mb + j * 8;
                    *(short8*)(dst + c) =
                        *(const short8*)(S + nl * 128 + (c ^ ((nl & 15) << 3)));
                }
            }
        }
        return;
    }

    const int r0 = g * 4;
#pragma unroll
    for (int mt = 0; mt < 2; ++mt) {
#pragma unroll
        for (int nt = 0; nt < 4; ++nt) {
            long n = n0 + wn + nt * 16 + lm;
            float bv = bias[n];
            // fold softmax scale (0.125*log2e) into Q columns at MODE 0
            float scq = (MODE == 0 && n < 1024) ? 0.18033688f : 1.0f;
#pragma unroll
            for (int r = 0; r < 4; ++r) {
                long m = m0 + wm + mt * 16 + r0 + r;
                float v = (acc[mt][nt][r] + bv) * scq;
                if (MODE == 0) o16[m * N + n] = f2bf(v);
                else           f_out[m * N + n] = v;
            }
        }
    }
}

// ---------------- 64x128-tile fp32-out GEMM (Wo projection), 512-thread ----------------
// 8 waves (2 wm x 4 wn), per-wave 32x32, acc[2][2]. 512 blocks = 2 blocks/CU
// -> 16 waves/CU (was 8 at 256 thr). launch_bounds(512,2): cap 128 VGPR.
__global__ __launch_bounds__(512, 2)
void gemm_bt64(const u16* __restrict__ A, const u16* __restrict__ Bt,
               const float* __restrict__ bias, float* __restrict__ f_out,
               int M, int N, int K) {
    __shared__ __attribute__((aligned(16))) u16 As[64 * 32];
    __shared__ __attribute__((aligned(16))) u16 Bs[128 * 32];
    const int tid = threadIdx.x;          // 0..511
    const int l = tid & 63;
    const int w = tid >> 6;               // 0..7
    const int wm = (w & 1) * 32, wn = (w >> 1) * 32;
    const long m0 = (long)blockIdx.x * 64, n0 = (long)blockIdx.y * 128;
    const int lm = l & 15, g = l >> 4;

    const int sr = tid >> 2;                       // 0..127
    const int sc = (tid & 3) ^ ((tid >> 3) & 3);
    const u16* Ag = A + (m0 + sr) * K + sc * 8;    // valid for tid<256 (sr<64)
    const u16* Bg = Bt + (n0 + sr) * K + sc * 8;
    u16* Asl = As + tid * 8;
    u16* Bsl = Bs + tid * 8;

    const int x0 = (lm >> 1) & 3;

    f32x4 acc[2][2] = {};

    for (int k0 = 0; k0 < K; k0 += 32) {
        __syncthreads();
        if (tid < 256) ldlds16(Ag + k0, Asl);
        ldlds16(Bg + k0, Bsl);
        __syncthreads();
        short8 af[2], bf[2];
#pragma unroll
        for (int mt = 0; mt < 2; ++mt)
            af[mt] = *(const short8*)(As + (wm + mt * 16 + lm) * 32 + ((g ^ x0) * 8));
#pragma unroll
        for (int nt = 0; nt < 2; ++nt)
            bf[nt] = *(const short8*)(Bs + (wn + nt * 16 + lm) * 32 + ((g ^ x0) * 8));
#pragma unroll
        for (int mt = 0; mt < 2; ++mt)
#pragma unroll
            for (int nt = 0; nt < 2; ++nt)
                acc[mt][nt] = __builtin_amdgcn_mfma_f32_16x16x32_bf16(
                    af[mt], bf[nt], acc[mt][nt], 0, 0, 0);
    }

    const int r0 = g * 4;
#pragma unroll
    for (int mt = 0; mt < 2; ++mt) {
#pragma unroll
        for (int nt = 0; nt < 2; ++nt) {
            long n = n0 + wn + nt * 16 + lm;
            float bv = bias[n];
#pragma unroll
            for (int r = 0; r < 4; ++r) {
                long m = m0 + wm + mt * 16 + r0 + r;
                f_out[m * N + n] = acc[mt][nt][r] + bv;
            }
        }
    }
}

// ---------------- flash attention: S^T formulation, zero P round-trip ----------------
// Exact R4 version (proven 43.2us): 512 threads = 8 waves, 4-way q-split (mh) x
// 2-way s-split (sh); XCD-aware bijective block swizzle (FETCH 91->12MB).
// R5's o_sum/v_perm/setprio VALU-diet lowered VALUBusy but regressed dur -> reverted.
// Q pre-scaled by 0.125*log2e in gemm_bt<0>, so softmax inner loop is bare exp2.
// LDS 64 KB: Ks[2] 128x64 @0/8192, Vs[2] 64x128 @16384/24576 (u16 idx).
__global__ __launch_bounds__(512, 4)
void attn(const u16* __restrict__ qkv, const u16* __restrict__ Vt,
          u16* __restrict__ Y) {
    __shared__ __attribute__((aligned(16))) u16 S_lds[32768];

    // XCD swizzle: lin = hw linear block id; residue class (lin&7) -> 64 blocks
    // = bh in [4c, 4c+4) x px 0..15, all co-resident on one XCD.
    const int lin = blockIdx.x + (blockIdx.y << 4);
    const int s = (lin & 7) * 64 + (lin >> 3);
    const int px = s & 15;                 // 0..15
    const int bh = s >> 4;                 // 0..31
    const int tid = threadIdx.x, l = tid & 63, w = tid >> 6;   // w 0..7
    const int mh = w >> 1, sh = w & 1;
    const int lm = l & 15, g = l >> 4;
    const int lm7 = lm & 7;
    const int mh16 = mh * 16, sh64 = sh * 64, sh8 = sh * 8, g4 = g * 4;
    const int b = bh >> 4, h = bh & 15;

    const u16* Kp = qkv + (long)b * Tn * 3072 + 1024 + h * 64;
    const u16* Vp = Vt + (long)bh * HDn * Tn;

    // 512-thread staging: K 64 rows/round (2 rounds), V 32 rows/round (2 rounds)
    const int soffK = (tid >> 3) * 3072 + (((tid & 7) ^ ((tid >> 3) & 7)) * 8);
    const int soffV = (tid >> 4) * Tn + (((tid & 15) ^ ((tid >> 4) & 15)) * 8);

    auto prefetch = [&](int i, int buf) {
        u16* Kn = S_lds + buf * 8192;
        u16* Vn = S_lds + 16384 + buf * 8192;
        const u16* Kt = Kp + (long)i * 128 * 3072;
        const u16* Vg = Vp + i * 128;
#pragma unroll
        for (int j = 0; j < 2; ++j) {
            ldlds16(Kt + j * (64 * 3072) + soffK, Kn + j * 4096 + tid * 8);
            ldlds16(Vg + j * (32 * Tn) + soffV, Vn + j * 4096 + tid * 8);
        }
    };

    for (int job = 0; job < 2; ++job) {
        const int qt = job ? px : 31 - px;
        const u16* Qp = qkv + ((long)b * Tn + qt * 64) * 3072 + h * 64;

        // Q fragments (B-operand of S^T mfma): Q[q=mh16+lm][d=hh*32+g*8+j]
        short8 qa[2];
#pragma unroll
        for (int hh = 0; hh < 2; ++hh)
            qa[hh] = *(const short8*)(Qp + (mh16 + lm) * 3072 + hh * 32 + g * 8);

        f32x4 o_acc[4] = {};          // O^T[d=dt*16+g4+r][q=mh16+lm]
        float lsum = 0.f;
        const int qrow = qt * 64 + mh16 + lm;

        prefetch(0, 0);
        __syncthreads();

        auto body = [&](int buf, int sbase, auto diag_c) {
            constexpr bool DIAG = decltype(diag_c)::value;
            const u16* Kc = S_lds + buf * 8192;
            const u16* Vc = S_lds + 16384 + buf * 8192;
            // S^T = K * Q^T : 1 q-tile x 4 s-tiles, k=64
            f32x4 st[4];
#pragma unroll
            for (int nt = 0; nt < 4; ++nt)
                st[nt] = (f32x4){0.f, 0.f, 0.f, 0.f};
#pragma unroll
            for (int nt = 0; nt < 4; ++nt)
#pragma unroll
                for (int hh = 0; hh < 2; ++hh) {
                    short8 kf = *(const short8*)(Kc + (sh64 + nt * 16 + lm) * 64 +
                                                 (((hh * 4 + g) ^ lm7) * 8));
                    st[nt] = __builtin_amdgcn_mfma_f32_16x16x32_bf16(kf, qa[hh], st[nt], 0, 0, 0);
                }
            // exp2 + mask + pack to bf16 B-fragments (P^T stays in registers)
            short4v pb[4];
#pragma unroll
            for (int nt = 0; nt < 4; ++nt) {
                const int scolb = sbase + sh64 + nt * 16 + g4;
#pragma unroll
                for (int r = 0; r < 4; ++r) {
                    float xx = st[nt][r];
                    if (DIAG && scolb + r > qrow) xx = -1e30f;
                    float p = exp2f(xx);
                    lsum += p;
                    pb[nt][r] = (short)(__float_as_uint(p) >> 16);
                }
            }
            // O^T += V^T * P^T : per (s-16-chunk, d-tile) one 16x16x16 MFMA
#pragma unroll
            for (int nt = 0; nt < 4; ++nt) {
                const int vcol = (((sh8 + nt * 2 + (g >> 1)) ^ lm) * 8) + (g & 1) * 4;
#pragma unroll
                for (int dt = 0; dt < 4; ++dt) {
                    short4v vf = *(const short4v*)(Vc + (dt * 16 + lm) * 128 + vcol);
                    o_acc[dt] = __builtin_amdgcn_mfma_f32_16x16x16bf16_1k(vf, pb[nt], o_acc[dt], 0, 0, 0);
                }
            }
        };

        const int n = (qt >> 1) + 1;     // 128-col iterations; last is DIAG
        if (n == 1) {
            body(0, 0, TrueT{});
        } else {
            int i = 0;
            for (; i + 2 <= n - 1; i += 2) {
                prefetch(i + 1, 1); body(0, i * 128, FalseT{}); __syncthreads();
                prefetch(i + 2, 0); body(1, (i + 1) * 128, FalseT{}); __syncthreads();
            }
            if (i == n - 2) {
                prefetch(n - 1, 1); body(0, i * 128, FalseT{}); __syncthreads();
                body(1, (n - 1) * 128, TrueT{});
            } else {  // i == n-1
                body(0, i * 128, TrueT{});
            }
        }

        // rowsum: sum across the 4 quads holding the same q=lm
        lsum += __shfl_xor(lsum, 16, 64);
        lsum += __shfl_xor(lsum, 32, 64);

        // ---- epilogue: cross-sh reduce + transpose via padded f32 LDS ----
        __syncthreads();
        float* Ytf = (float*)S_lds;               // [64][68] f32 (17408 B)
        float* redl = (float*)(S_lds + 8704);     // 64 f32

        if (sh == 1) {
            const int q = mh16 + lm;
#pragma unroll
            for (int dt = 0; dt < 4; ++dt)
                *(f32x4*)(Ytf + q * 68 + dt * 16 + g4) = o_acc[dt];
            if (g == 0) redl[q] = lsum;
        }
        __syncthreads();
        if (sh == 0) {
            const int q = mh16 + lm;
            float inv = 1.0f / (lsum + redl[q]);
#pragma unroll
            for (int dt = 0; dt < 4; ++dt) {
                f32x4 t = *(const f32x4*)(Ytf + q * 68 + dt * 16 + g4);
                t += o_acc[dt];
                t *= inv;
                *(f32x4*)(Ytf + q * 68 + dt * 16 + g4) = t;
            }
        }
        __syncthreads();
        {   // coalesced store: 8 threads per q-row, 8 bf16 each
            const int q = tid >> 3, dseg = (tid & 7) * 8;
            long base = ((long)b * Tn + qt * 64 + q) * Cn + h * HDn + dseg;
            u16 tmp[8];
#pragma unroll
            for (int j = 0; j < 8; ++j)
                tmp[j] = f2bf(Ytf[q * 68 + dseg + j]);
            *(short8*)(Y + base) = *(const short8*)tmp;
        }
        __syncthreads();   // LDS reads done before next job restages
    }
}

extern "C" void kernel_launch(void* const* d_in, const int* in_sizes, int n_in,
                              void* d_out, int out_size, void* d_ws, size_t ws_size,
                              hipStream_t stream) {
    const float* x    = (const float*)d_in[0];
    const float* Wqkv = (const float*)d_in[1];
    const float* bqkv = (const float*)d_in[2];
    const float* Wo   = (const float*)d_in[3];
    const float* bo   = (const float*)d_in[4];
    float* out = (float*)d_out;

    u16* xb    = (u16*)d_ws;          // 4M u16 : x bf16
    u16* wqkvt = xb + 4194304;        // 3M : Wqkv^T
    u16* wot   = wqkvt + 3145728;     // 1M : Wo^T
    u16* qkvb  = wot + 1048576;       // 12M : qkv [b,t,3C] bf16 (Q pre-scaled; V third unused)
    u16* vtb   = qkvb + 12582912;     // 4M : V^T [b,h,d,t] (written by gemm_bt<0>)
    u16* yb    = vtb + 4194304;       // 4M : attn out [b,t,c]

    prep<<<5120, 256, 0, stream>>>(x, xb, Wqkv, wqkvt, Wo, wot);
    gemm_bt<0><<<dim3(32, 24), 512, 0, stream>>>(xb, wqkvt, bqkv, qkvb, vtb,
                                                 nullptr, 4096, 3072, 1024);
    attn<<<dim3(16, 32), 512, 0, stream>>>(qkvb, vtb, yb);
    gemm_bt64<<<dim3(64, 8), 512, 0, stream>>>(yb, wot, bo, out, 4096, 1024, 1024);
}

// Round 7
// 165.102 us; speedup vs baseline: 1.1705x; 1.0456x over previous
//
#include <hip/hip_runtime.h>

typedef unsigned short u16;
typedef __attribute__((ext_vector_type(8))) short short8;
typedef __attribute__((ext_vector_type(4))) short short4v;
typedef __attribute__((ext_vector_type(4))) float f32x4;
typedef __attribute__((ext_vector_type(4))) float float4v;
typedef __attribute__((ext_vector_type(4))) unsigned short u16x4;

#define AS1 __attribute__((address_space(1)))
#define AS3 __attribute__((address_space(3)))

// B=2, T=2048, C=1024, H=16, HD=64
#define Tn 2048
#define Cn 1024
#define Hn 16
#define HDn 64

#if __has_builtin(__builtin_amdgcn_exp2f)
#define EXP2(x) __builtin_amdgcn_exp2f(x)   // bare v_exp_f32 (no ocml denorm fixup)
#else
#define EXP2(x) exp2f(x)
#endif

struct FalseT { static constexpr bool value = false; };
struct TrueT  { static constexpr bool value = true;  };

static __device__ __forceinline__ u16 f2bf(float f) {
    unsigned int u = __float_as_uint(f);
    u += 0x7FFFu + ((u >> 16) & 1u);   // round-to-nearest-even
    return (u16)(u >> 16);
}

static __device__ __forceinline__ void ldlds16(const void* g, void* l) {
    __builtin_amdgcn_global_load_lds((const AS1 unsigned int*)g,
                                     (AS3 unsigned int*)l, 16, 0, 0);
}

// ---------------- fused prep: x->bf16 | Wqkv^T->bf16 | Wo^T->bf16 ----------------
__global__ void prep(const float* __restrict__ x, u16* __restrict__ xb,
                     const float* __restrict__ Wqkv, u16* __restrict__ wqkvt,
                     const float* __restrict__ Wo, u16* __restrict__ wot) {
    __shared__ float t[64][65];
    const int bx = blockIdx.x, tid = threadIdx.x;
    if (bx < 4096) {
        int i = bx * 256 + tid;
        float4v v = ((const float4v*)x)[i];
        u16x4 o;
        o.x = f2bf(v.x); o.y = f2bf(v.y); o.z = f2bf(v.z); o.w = f2bf(v.w);
        ((u16x4*)xb)[i] = o;
        return;
    }
    const float* in; u16* out; int R, Cc, r0, c0;
    if (bx < 4864) {
        int idx = bx - 4096;
        in = Wqkv; out = wqkvt; R = 1024; Cc = 3072;
        c0 = (idx % 48) * 64; r0 = (idx / 48) * 64;
    } else {
        int idx = bx - 4864;
        in = Wo; out = wot; R = 1024; Cc = 1024;
        c0 = (idx & 15) * 64; r0 = (idx >> 4) * 64;
    }
    int tx = tid & 63, ty = tid >> 6;
#pragma unroll
    for (int i = 0; i < 64; i += 4)
        t[ty + i][tx] = in[(long)(r0 + ty + i) * Cc + c0 + tx];
    __syncthreads();
#pragma unroll
    for (int i = 0; i < 64; i += 4)
        out[(long)(c0 + ty + i) * R + r0 + tx] = f2bf(t[tx][ty + i]);
}

// ---------------- m97-style GEMM, BK=64: C[M][N] = A[M][K] * Bt[N][K]^T + bias ----
// 256 threads, 128x128 tile, K-step 64 (32KB LDS): 32 MFMAs per barrier pair vs 8
// in the BK=32 shape -> 4x barrier amortization (the vmcnt(0)+barrier drain is the
// known ~20% structural stall of the 2-phase shape). acc[4][4]; (256,3) VGPR cap
// ~170 >> est ~110 (the 512-thr variant would sit at its ~85 cap -> spill risk).
// Staging: slot s=tid+j*256, row=s>>3, global col pre-XORed by row&7, linear LDS
// dest; read-side applies the same XOR ((kk*4+g)^(lm&7)) -- both-sides involution.
// MODE 0: bf16 out; softmax scale folded into Q cols (n<1024); V-blocks (n0>=2048)
// transpose via LDS (reusing As) and emit V^T directly.  MODE 1: fp32 out.
template <int MODE>
__global__ __launch_bounds__(256, 3)
void gemm_bt(const u16* __restrict__ A, const u16* __restrict__ Bt,
             const float* __restrict__ bias,
             u16* __restrict__ o16, u16* __restrict__ vout,
             float* __restrict__ f_out,
             int M, int N, int K) {
    __shared__ __attribute__((aligned(16))) u16 As[128 * 64];
    __shared__ __attribute__((aligned(16))) u16 Bs[128 * 64];
    const int tid = threadIdx.x;
    const int l = tid & 63;
    const int w = tid >> 6;
    const int wm = (w >> 1) * 64, wn = (w & 1) * 64;
    const long m0 = (long)blockIdx.x * 128, n0 = (long)blockIdx.y * 128;
    const int lm = l & 15, g = l >> 4;

    const int sr = tid >> 3;                         // 0..31 (row base, j adds 32)
    const int scx = (tid & 7) ^ ((tid >> 3) & 7);    // pre-swizzled col segment
    const u16* Ag = A + (m0 + sr) * K + scx * 8;
    const u16* Bg = Bt + (n0 + sr) * K + scx * 8;
    u16* Asl = As + tid * 8;
    u16* Bsl = Bs + tid * 8;
    const int xr = lm & 7;                           // read-side row XOR

    f32x4 acc[4][4] = {};

    for (int k0 = 0; k0 < K; k0 += 64) {
        __syncthreads();
#pragma unroll
        for (int j = 0; j < 4; ++j) {
            ldlds16(Ag + k0 + (long)(j * 32) * K, Asl + j * 2048);
            ldlds16(Bg + k0 + (long)(j * 32) * K, Bsl + j * 2048);
        }
        __syncthreads();
#pragma unroll
        for (int kk = 0; kk < 2; ++kk) {
            const int cs0 = ((kk * 4 + g) ^ xr) * 8;
            short8 af[4], bf[4];
#pragma unroll
            for (int mt = 0; mt < 4; ++mt)
                af[mt] = *(const short8*)(As + (wm + mt * 16 + lm) * 64 + cs0);
#pragma unroll
            for (int nt = 0; nt < 4; ++nt)
                bf[nt] = *(const short8*)(Bs + (wn + nt * 16 + lm) * 64 + cs0);
#pragma unroll
            for (int mt = 0; mt < 4; ++mt)
#pragma unroll
                for (int nt = 0; nt < 4; ++nt)
                    acc[mt][nt] = __builtin_amdgcn_mfma_f32_16x16x32_bf16(
                        af[mt], bf[nt], acc[mt][nt], 0, 0, 0);
        }
    }

    if (MODE == 0 && n0 >= 2048) {
        // ---- fused V^T emit: transpose 128x128 tile via 16KB LDS (As), 2 passes ----
        const long b = m0 >> 11;
        const int t0 = (int)(m0 & 2047);
        const int n0b = (int)(n0 - 2048);
#pragma unroll
        for (int p = 0; p < 2; ++p) {
            __syncthreads();               // prior LDS reads (k-loop / pass p-1) done
            if ((w & 1) == p) {            // waves whose wn == p*64 hold this n-half
#pragma unroll
                for (int mt = 0; mt < 4; ++mt) {
                    const int colu = wm + mt * 16 + g * 4;   // m_local base (4-aligned)
#pragma unroll
                    for (int nt = 0; nt < 4; ++nt) {
                        const int row = nt * 16 + lm;        // n_local in 0..63
                        float bv = bias[n0 + p * 64 + row];
                        u16 tmp[4];
#pragma unroll
                        for (int r = 0; r < 4; ++r)
                            tmp[r] = f2bf(acc[mt][nt][r] + bv);
                        // XOR-swizzle columns by row to avoid 16-way write conflicts
                        *(u16x4*)(As + row * 128 + (colu ^ (lm << 3))) = *(const u16x4*)tmp;
                    }
                }
            }
            __syncthreads();
            {   // coalesced V^T store: 4 threads per n-row, 64B each along t
                const int nl = tid >> 2, mb = (tid & 3) * 32;
                const int ng = n0b + p * 64 + nl;
                u16* dst = vout + (((b * 16 + (ng >> 6)) * 64 + (ng & 63)) * (long)Tn) + t0;
#pragma unroll
                for (int j = 0; j < 4; ++j) {
                    const int c = mb + j * 8;
                    *(short8*)(dst + c) =
                        *(const short8*)(As + nl * 128 + (c ^ ((nl & 15) << 3)));
                }
            }
        }
        return;
    }

    const int r0 = (l >> 4) * 4;
#pragma unroll
    for (int mt = 0; mt < 4; ++mt) {
#pragma unroll
        for (int nt = 0; nt < 4; ++nt) {
            long n = n0 + wn + nt * 16 + lm;
            float bv = bias[n];
            // fold softmax scale (0.125*log2e) into Q columns at MODE 0
            float scq = (MODE == 0 && n < 1024) ? 0.18033688f : 1.0f;
#pragma unroll
            for (int r = 0; r < 4; ++r) {
                long m = m0 + wm + mt * 16 + r0 + r;
                float v = (acc[mt][nt][r] + bv) * scq;
                if (MODE == 0) o16[m * N + n] = f2bf(v);
                else           f_out[m * N + n] = v;
            }
        }
    }
}

// ---------------- 64x128-tile fp32-out GEMM (Wo projection), 512-thread ----------------
// 8 waves (2 wm x 4 wn), per-wave 32x32, acc[2][2]. 512 blocks = 2 blocks/CU
// -> 16 waves/CU. launch_bounds(512,2): cap 128 VGPR. (unchanged from R6)
__global__ __launch_bounds__(512, 2)
void gemm_bt64(const u16* __restrict__ A, const u16* __restrict__ Bt,
               const float* __restrict__ bias, float* __restrict__ f_out,
               int M, int N, int K) {
    __shared__ __attribute__((aligned(16))) u16 As[64 * 32];
    __shared__ __attribute__((aligned(16))) u16 Bs[128 * 32];
    const int tid = threadIdx.x;          // 0..511
    const int l = tid & 63;
    const int w = tid >> 6;               // 0..7
    const int wm = (w & 1) * 32, wn = (w >> 1) * 32;
    const long m0 = (long)blockIdx.x * 64, n0 = (long)blockIdx.y * 128;
    const int lm = l & 15, g = l >> 4;

    const int sr = tid >> 2;                       // 0..127
    const int sc = (tid & 3) ^ ((tid >> 3) & 3);
    const u16* Ag = A + (m0 + sr) * K + sc * 8;    // valid for tid<256 (sr<64)
    const u16* Bg = Bt + (n0 + sr) * K + sc * 8;
    u16* Asl = As + tid * 8;
    u16* Bsl = Bs + tid * 8;

    const int x0 = (lm >> 1) & 3;

    f32x4 acc[2][2] = {};

    for (int k0 = 0; k0 < K; k0 += 32) {
        __syncthreads();
        if (tid < 256) ldlds16(Ag + k0, Asl);
        ldlds16(Bg + k0, Bsl);
        __syncthreads();
        short8 af[2], bf[2];
#pragma unroll
        for (int mt = 0; mt < 2; ++mt)
            af[mt] = *(const short8*)(As + (wm + mt * 16 + lm) * 32 + ((g ^ x0) * 8));
#pragma unroll
        for (int nt = 0; nt < 2; ++nt)
            bf[nt] = *(const short8*)(Bs + (wn + nt * 16 + lm) * 32 + ((g ^ x0) * 8));
#pragma unroll
        for (int mt = 0; mt < 2; ++mt)
#pragma unroll
            for (int nt = 0; nt < 2; ++nt)
                acc[mt][nt] = __builtin_amdgcn_mfma_f32_16x16x32_bf16(
                    af[mt], bf[nt], acc[mt][nt], 0, 0, 0);
    }

    const int r0 = g * 4;
#pragma unroll
    for (int mt = 0; mt < 2; ++mt) {
#pragma unroll
        for (int nt = 0; nt < 2; ++nt) {
            long n = n0 + wn + nt * 16 + lm;
            float bv = bias[n];
#pragma unroll
            for (int r = 0; r < 4; ++r) {
                long m = m0 + wm + mt * 16 + r0 + r;
                f_out[m * N + n] = acc[mt][nt][r] + bv;
            }
        }
    }
}

// ---------------- flash attention: S^T formulation, zero P round-trip ----------------
// Exact R6 version except EXP2 (bare v_exp_f32 instead of ocml exp2f fixup path).
// 512 threads = 8 waves, 4-way q-split (mh) x 2-way s-split (sh); XCD-aware
// bijective block swizzle (FETCH 91->12MB). Q pre-scaled by 0.125*log2e in
// gemm_bt<0>, so softmax inner loop is bare exp2.
// LDS 64 KB: Ks[2] 128x64 @0/8192, Vs[2] 64x128 @16384/24576 (u16 idx).
__global__ __launch_bounds__(512, 4)
void attn(const u16* __restrict__ qkv, const u16* __restrict__ Vt,
          u16* __restrict__ Y) {
    __shared__ __attribute__((aligned(16))) u16 S_lds[32768];

    // XCD swizzle: lin = hw linear block id; residue class (lin&7) -> 64 blocks
    // = bh in [4c, 4c+4) x px 0..15, all co-resident on one XCD.
    const int lin = blockIdx.x + (blockIdx.y << 4);
    const int s = (lin & 7) * 64 + (lin >> 3);
    const int px = s & 15;                 // 0..15
    const int bh = s >> 4;                 // 0..31
    const int tid = threadIdx.x, l = tid & 63, w = tid >> 6;   // w 0..7
    const int mh = w >> 1, sh = w & 1;
    const int lm = l & 15, g = l >> 4;
    const int lm7 = lm & 7;
    const int mh16 = mh * 16, sh64 = sh * 64, sh8 = sh * 8, g4 = g * 4;
    const int b = bh >> 4, h = bh & 15;

    const u16* Kp = qkv + (long)b * Tn * 3072 + 1024 + h * 64;
    const u16* Vp = Vt + (long)bh * HDn * Tn;

    // 512-thread staging: K 64 rows/round (2 rounds), V 32 rows/round (2 rounds)
    const int soffK = (tid >> 3) * 3072 + (((tid & 7) ^ ((tid >> 3) & 7)) * 8);
    const int soffV = (tid >> 4) * Tn + (((tid & 15) ^ ((tid >> 4) & 15)) * 8);

    auto prefetch = [&](int i, int buf) {
        u16* Kn = S_lds + buf * 8192;
        u16* Vn = S_lds + 16384 + buf * 8192;
        const u16* Kt = Kp + (long)i * 128 * 3072;
        const u16* Vg = Vp + i * 128;
#pragma unroll
        for (int j = 0; j < 2; ++j) {
            ldlds16(Kt + j * (64 * 3072) + soffK, Kn + j * 4096 + tid * 8);
            ldlds16(Vg + j * (32 * Tn) + soffV, Vn + j * 4096 + tid * 8);
        }
    };

    for (int job = 0; job < 2; ++job) {
        const int qt = job ? px : 31 - px;
        const u16* Qp = qkv + ((long)b * Tn + qt * 64) * 3072 + h * 64;

        // Q fragments (B-operand of S^T mfma): Q[q=mh16+lm][d=hh*32+g*8+j]
        short8 qa[2];
#pragma unroll
        for (int hh = 0; hh < 2; ++hh)
            qa[hh] = *(const short8*)(Qp + (mh16 + lm) * 3072 + hh * 32 + g * 8);

        f32x4 o_acc[4] = {};          // O^T[d=dt*16+g4+r][q=mh16+lm]
        float lsum = 0.f;
        const int qrow = qt * 64 + mh16 + lm;

        prefetch(0, 0);
        __syncthreads();

        auto body = [&](int buf, int sbase, auto diag_c) {
            constexpr bool DIAG = decltype(diag_c)::value;
            const u16* Kc = S_lds + buf * 8192;
            const u16* Vc = S_lds + 16384 + buf * 8192;
            // S^T = K * Q^T : 1 q-tile x 4 s-tiles, k=64
            f32x4 st[4];
#pragma unroll
            for (int nt = 0; nt < 4; ++nt)
                st[nt] = (f32x4){0.f, 0.f, 0.f, 0.f};
#pragma unroll
            for (int nt = 0; nt < 4; ++nt)
#pragma unroll
                for (int hh = 0; hh < 2; ++hh) {
                    short8 kf = *(const short8*)(Kc + (sh64 + nt * 16 + lm) * 64 +
                                                 (((hh * 4 + g) ^ lm7) * 8));
                    st[nt] = __builtin_amdgcn_mfma_f32_16x16x32_bf16(kf, qa[hh], st[nt], 0, 0, 0);
                }
            // exp2 + mask + pack to bf16 B-fragments (P^T stays in registers)
            short4v pb[4];
#pragma unroll
            for (int nt = 0; nt < 4; ++nt) {
                const int scolb = sbase + sh64 + nt * 16 + g4;
#pragma unroll
                for (int r = 0; r < 4; ++r) {
                    float xx = st[nt][r];
                    if (DIAG && scolb + r > qrow) xx = -1e30f;
                    float p = EXP2(xx);
                    lsum += p;
                    pb[nt][r] = (short)(__float_as_uint(p) >> 16);
                }
            }
            // O^T += V^T * P^T : per (s-16-chunk, d-tile) one 16x16x16 MFMA
#pragma unroll
            for (int nt = 0; nt < 4; ++nt) {
                const int vcol = (((sh8 + nt * 2 + (g >> 1)) ^ lm) * 8) + (g & 1) * 4;
#pragma unroll
                for (int dt = 0; dt < 4; ++dt) {
                    short4v vf = *(const short4v*)(Vc + (dt * 16 + lm) * 128 + vcol);
                    o_acc[dt] = __builtin_amdgcn_mfma_f32_16x16x16bf16_1k(vf, pb[nt], o_acc[dt], 0, 0, 0);
                }
            }
        };

        const int n = (qt >> 1) + 1;     // 128-col iterations; last is DIAG
        if (n == 1) {
            body(0, 0, TrueT{});
        } else {
            int i = 0;
            for (; i + 2 <= n - 1; i += 2) {
                prefetch(i + 1, 1); body(0, i * 128, FalseT{}); __syncthreads();
                prefetch(i + 2, 0); body(1, (i + 1) * 128, FalseT{}); __syncthreads();
            }
            if (i == n - 2) {
                prefetch(n - 1, 1); body(0, i * 128, FalseT{}); __syncthreads();
                body(1, (n - 1) * 128, TrueT{});
            } else {  // i == n-1
                body(0, i * 128, TrueT{});
            }
        }

        // rowsum: sum across the 4 quads holding the same q=lm
        lsum += __shfl_xor(lsum, 16, 64);
        lsum += __shfl_xor(lsum, 32, 64);

        // ---- epilogue: cross-sh reduce + transpose via padded f32 LDS ----
        __syncthreads();
        float* Ytf = (float*)S_lds;               // [64][68] f32 (17408 B)
        float* redl = (float*)(S_lds + 8704);     // 64 f32

        if (sh == 1) {
            const int q = mh16 + lm;
#pragma unroll
            for (int dt = 0; dt < 4; ++dt)
                *(f32x4*)(Ytf + q * 68 + dt * 16 + g4) = o_acc[dt];
            if (g == 0) redl[q] = lsum;
        }
        __syncthreads();
        if (sh == 0) {
            const int q = mh16 + lm;
            float inv = 1.0f / (lsum + redl[q]);
#pragma unroll
            for (int dt = 0; dt < 4; ++dt) {
                f32x4 t = *(const f32x4*)(Ytf + q * 68 + dt * 16 + g4);
                t += o_acc[dt];
                t *= inv;
                *(f32x4*)(Ytf + q * 68 + dt * 16 + g4) = t;
            }
        }
        __syncthreads();
        {   // coalesced store: 8 threads per q-row, 8 bf16 each
            const int q = tid >> 3, dseg = (tid & 7) * 8;
            long base = ((long)b * Tn + qt * 64 + q) * Cn + h * HDn + dseg;
            u16 tmp[8];
#pragma unroll
            for (int j = 0; j < 8; ++j)
                tmp[j] = f2bf(Ytf[q * 68 + dseg + j]);
            *(short8*)(Y + base) = *(const short8*)tmp;
        }
        __syncthreads();   // LDS reads done before next job restages
    }
}

extern "C" void kernel_launch(void* const* d_in, const int* in_sizes, int n_in,
                              void* d_out, int out_size, void* d_ws, size_t ws_size,
                              hipStream_t stream) {
    const float* x    = (const float*)d_in[0];
    const float* Wqkv = (const float*)d_in[1];
    const float* bqkv = (const float*)d_in[2];
    const float* Wo   = (const float*)d_in[3];
    const float* bo   = (const float*)d_in[4];
    float* out = (float*)d_out;

    u16* xb    = (u16*)d_ws;          // 4M u16 : x bf16
    u16* wqkvt = xb + 4194304;        // 3M : Wqkv^T
    u16* wot   = wqkvt + 3145728;     // 1M : Wo^T
    u16* qkvb  = wot + 1048576;       // 12M : qkv [b,t,3C] bf16 (Q pre-scaled; V third unused)
    u16* vtb   = qkvb + 12582912;     // 4M : V^T [b,h,d,t] (written by gemm_bt<0>)
    u16* yb    = vtb + 4194304;       // 4M : attn out [b,t,c]

    prep<<<5120, 256, 0, stream>>>(x, xb, Wqkv, wqkvt, Wo, wot);
    gemm_bt<0><<<dim3(32, 24), 256, 0, stream>>>(xb, wqkvt, bqkv, qkvb, vtb,
                                                 nullptr, 4096, 3072, 1024);
    attn<<<dim3(16, 32), 512, 0, stream>>>(qkvb, vtb, yb);
    gemm_bt64<<<dim3(64, 8), 512, 0, stream>>>(yb, wot, bo, out, 4096, 1024, 1024);
}